// Round 9
// baseline (257.303 us; speedup 1.0000x reference)
//
#include <hip/hip_runtime.h>

// ---------------------------------------------------------------------------
// MAB block: Qp=Q@Wq^T+bq; Kp/Vp from K; O=softmax(QhKh^T/8)Vh; X=LN(O+Qp);
// h1=relu(X@W1^T+b1); h2=relu(h1@W2^T+b2); Off=h2@W3^T+b3; out=LN(X+Off).
// R7/R8: attn dbuf + counted vmcnt + XCD decode + QBLK=128. (44 -> ~26 us)
// R12: fp8 FFN3 + FFN1 dbuf/XCD. R13: fp8 FFN1 (252.6us, absmax 0.074).
// R14: ffn1/ffn2 tile widened to 128x256, 8 waves (512 thr). Per-wave work,
//     VGPR and the single-buffer drain skeleton are IDENTICAL to the proven
//     128x128 form (each wave still owns 64x64, acc[2][2]); only the B-tile
//     and wn-range grow. LDS 48KB -> 3 blk/CU = 24 waves; grid halves to
//     512 blocks; A-panel L2 staging traffic per output halves.
//     ffn3 keeps BN=128 (its grid would drop to 1 blk/CU at BN=256).
// ---------------------------------------------------------------------------

typedef __bf16 bf16_t;
typedef __bf16 bf16x8 __attribute__((ext_vector_type(8)));
typedef __bf16 bf16x4 __attribute__((ext_vector_type(4)));
typedef __bf16 bf16x2 __attribute__((ext_vector_type(2)));
typedef float  f32x4  __attribute__((ext_vector_type(4)));
typedef float  f32x16 __attribute__((ext_vector_type(16)));
typedef int    i32x4_t __attribute__((ext_vector_type(4)));
typedef int    i32x8_t __attribute__((ext_vector_type(8)));

__device__ __forceinline__ f32x4 mfma16(bf16x8 a, bf16x8 b, f32x4 c) {
  return __builtin_amdgcn_mfma_f32_16x16x32_bf16(a, b, c, 0, 0, 0);
}

// async global->LDS, 16B per lane. LDS dst is wave-uniform base + lane*16.
__device__ __forceinline__ void gload_lds16(const void* g, void* l) {
  __builtin_amdgcn_global_load_lds((const __attribute__((address_space(1))) void*)g,
                                   (__attribute__((address_space(3))) void*)l,
                                   16, 0, 0);
}

__device__ __forceinline__ unsigned char to_fp8(float v) {
  return (unsigned char)(__builtin_amdgcn_cvt_pk_fp8_f32(v, v, 0, false) & 0xff);
}

// ---------------------------------------------------------------------------
// Fused f32 -> bf16 cast of Q, K, Wq/Wk/Wv; W1, W2, W3 -> fp8 e4m3.
// ---------------------------------------------------------------------------
__global__ __launch_bounds__(256) void cast_all(
    const float* __restrict__ Q, const float* __restrict__ K,
    const float* __restrict__ Wq, const float* __restrict__ Wk,
    const float* __restrict__ Wv, const float* __restrict__ W1,
    const float* __restrict__ W2, const float* __restrict__ W3,
    bf16_t* Qb, bf16_t* Kb, bf16_t* Wqb, bf16_t* Wkb, bf16_t* Wvb,
    unsigned char* W1q, unsigned char* W2q, unsigned char* W3q)
{
  long i = ((long)blockIdx.x * 256 + threadIdx.x) * 4;
  if (i >= 9175040L) {                            // W1 / W2 / W3 -> fp8
    const float* s; unsigned char* d; long o;
    if      (i < 10223616L) { s = W1; d = W1q; o = i - 9175040L;  }
    else if (i < 14417920L) { s = W2; d = W2q; o = i - 10223616L; }
    else                    { s = W3; d = W3q; o = i - 14417920L; }
    float4 v = *(const float4*)(s + o);
    unsigned int lo = __builtin_amdgcn_cvt_pk_fp8_f32(v.x, v.y, 0, false);
    unsigned int hi = __builtin_amdgcn_cvt_pk_fp8_f32(v.z, v.w, 0, false);
    *(unsigned int*)(d + o) = (lo & 0xffffu) | (hi << 16);
    return;
  }
  const float* s; bf16_t* d; long o;
  if      (i <  4194304L) { s = Q;  d = Qb;  o = i;             }
  else if (i <  8388608L) { s = K;  d = Kb;  o = i - 4194304L;  }
  else if (i <  8650752L) { s = Wq; d = Wqb; o = i - 8388608L;  }
  else if (i <  8912896L) { s = Wk; d = Wkb; o = i - 8650752L;  }
  else                    { s = Wv; d = Wvb; o = i - 8912896L;  }
  float4 v = *(const float4*)(s + o);
  bf16x4 w;
  w[0] = (bf16_t)v.x; w[1] = (bf16_t)v.y; w[2] = (bf16_t)v.z; w[3] = (bf16_t)v.w;
  *(bf16x4*)(d + o) = w;
}

// ---------------------------------------------------------------------------
// bf16 GEMM core (proj3 only now): C = A @ W^T (+bias). BM=BN=128, BK=64.
// Single-buffer 32KB (33KB w/ VTEPI) + drain loop (4-5 blk/CU).
// ---------------------------------------------------------------------------
template <bool VTEPI>
__device__ __forceinline__ void gemm_core(
    const bf16_t* __restrict__ A, const bf16_t* __restrict__ W,
    const float* __restrict__ bias,
    bf16_t* __restrict__ Cb, bf16_t* __restrict__ VTout,
    float bscale, int N, int K, int lda, int ldb, int bx, int by)
{
  constexpr int FI = 4;
  constexpr int FJ = 4;
  constexpr int CN = 64;
  constexpr int SM_AB = 256 * 64 * 2;             // 32 KB
  constexpr int SM_TS = 128 * 132 * 2;            // 33 KB VTEPI transpose
  constexpr int SMEM = (VTEPI && SM_TS > SM_AB) ? SM_TS : SM_AB;

  __shared__ __align__(16) char smem[SMEM];

  const int tid  = threadIdx.x;
  const int wave = tid >> 6, lane = tid & 63;
  const int lq   = lane & 15, quad = lane >> 4;
  const int wm   = wave & 1;
  const int wn   = wave >> 1;
  const long row0 = (long)bx * 128;
  const long col0 = (long)by * 128;

  const int sr = tid >> 3;
  const int cg = (tid & 7) ^ (sr & 7);
  const bf16_t* ag = A + (row0 + sr) * (long)lda + cg * 8;
  const bf16_t* bg = W + (col0 + sr) * (long)ldb + cg * 8;
  const int asOff = wave * 1024;
  const int bsOff = 128 * 128 + wave * 1024;
  const long arows32 = 32L * lda;
  const long brows32 = 32L * ldb;

  auto stage = [&](int k0) {
#pragma unroll
    for (int is = 0; is < 4; is++)
      gload_lds16(ag + is * arows32 + k0, smem + asOff + is * 4096);
#pragma unroll
    for (int is = 0; is < 4; is++)
      gload_lds16(bg + is * brows32 + k0, smem + bsOff + is * 4096);
  };

  const int off0 = (quad ^ (lq & 7)) * 8;
  const int aO0 = ((wm * 64 + lq) * 64 + off0) * 2;
  const int aO1 = ((wm * 64 + lq) * 64 + (off0 ^ 32)) * 2;
  const int bO0 = 128 * 128 + ((wn * CN + lq) * 64 + off0) * 2;
  const int bO1 = 128 * 128 + ((wn * CN + lq) * 64 + (off0 ^ 32)) * 2;

  f32x4 acc[FI][FJ];
#pragma unroll
  for (int i = 0; i < FI; i++)
#pragma unroll
    for (int j = 0; j < FJ; j++) acc[i][j] = (f32x4){0.f, 0.f, 0.f, 0.f};

  const int nt = K >> 6;
  for (int t = 0; t < nt; ++t) {
    __syncthreads();
    stage(t * 64);
    __syncthreads();

    bf16x8 af[FI], bw[FJ];
#pragma unroll
    for (int i = 0; i < FI; i++) af[i] = *(const bf16x8*)(smem + aO0 + i * 2048);
#pragma unroll
    for (int j = 0; j < FJ; j++) bw[j] = *(const bf16x8*)(smem + bO0 + j * 2048);
#pragma unroll
    for (int i = 0; i < FI; i++)
#pragma unroll
      for (int j = 0; j < FJ; j++)
        acc[i][j] = mfma16(af[i], bw[j], acc[i][j]);
#pragma unroll
    for (int i = 0; i < FI; i++) af[i] = *(const bf16x8*)(smem + aO1 + i * 2048);
#pragma unroll
    for (int j = 0; j < FJ; j++) bw[j] = *(const bf16x8*)(smem + bO1 + j * 2048);
#pragma unroll
    for (int i = 0; i < FI; i++)
#pragma unroll
      for (int j = 0; j < FJ; j++)
        acc[i][j] = mfma16(af[i], bw[j], acc[i][j]);
  }

  float bc[FJ];
#pragma unroll
  for (int j = 0; j < FJ; j++)
    bc[j] = bias ? bias[col0 + wn * CN + j * 16 + lq] : 0.f;

  if (VTEPI && VTout) {
    bf16_t* Ts = (bf16_t*)smem;
    __syncthreads();
#pragma unroll
    for (int i = 0; i < FI; i++)
#pragma unroll
      for (int j = 0; j < FJ; j++) {
        bf16x4 pv;
#pragma unroll
        for (int r = 0; r < 4; r++) pv[r] = (bf16_t)(acc[i][j][r] + bc[j]);
        *(bf16x4*)(Ts + (wn * CN + j * 16 + lq) * 132 + wm * 64 + i * 16 + quad * 4) = pv;
      }
    __syncthreads();
    const int b  = bx >> 3;
    const int mb = (bx & 7) * 128;
    const int h0 = by * 2;
    const int dd = tid >> 4;
    const int mc = (tid & 15) * 8;
#pragma unroll
    for (int p = 0; p < 8; p++) {
      const int d = dd + p * 16;
      bf16x8 v = *(const bf16x8*)(Ts + d * 132 + mc);
      *(bf16x8*)(VTout + ((long)(b * 8 + h0 + (d >> 6))) * 65536
                 + (d & 63) * 1024 + mb + mc) = v;
    }
    return;
  }

  const long rb = row0 + wm * 64 + quad * 4;
  const long cb = col0 + wn * CN + lq;
#pragma unroll
  for (int i = 0; i < FI; i++)
#pragma unroll
    for (int j = 0; j < FJ; j++)
#pragma unroll
      for (int r = 0; r < 4; r++) {
        float v = acc[i][j][r] + bc[j];
        long idx = (rb + i * 16 + r) * (long)N + cb + j * 16;
        if (Cb) Cb[idx] = (bf16_t)(v * bscale);
      }
}

// Fused Q/K/V projection; z==2 (V) writes transposed VT via VTEPI epilogue.
__global__ __launch_bounds__(256) void proj3(
    const bf16_t* __restrict__ Qb, const bf16_t* __restrict__ Kb,
    const bf16_t* __restrict__ Wqb, const bf16_t* __restrict__ Wkb,
    const bf16_t* __restrict__ Wvb,
    const float* __restrict__ bq, const float* __restrict__ bk,
    const float* __restrict__ bv,
    bf16_t* Qpb, bf16_t* Kpb, bf16_t* VT)
{
  const int z = blockIdx.z;
  const bf16_t* A  = (z == 0) ? Qb : Kb;
  const bf16_t* Wt = (z == 0) ? Wqb : ((z == 1) ? Wkb : Wvb);
  const float* bias = (z == 0) ? bq : ((z == 1) ? bk : bv);
  bf16_t* Cb = (z == 0) ? Qpb : ((z == 1) ? Kpb : nullptr);
  bf16_t* VTout = (z == 2) ? VT : nullptr;
  const float sc = (z == 1) ? 0.125f : 1.0f;
  gemm_core<true>(A, Wt, bias, Cb, VTout, sc,
                  512, 512, 512, 512, blockIdx.x, blockIdx.y);
}

// ---------------------------------------------------------------------------
// fp8 GEMM (shared body): C[M,N] = act(A_fp8[M,K] @ B_fp8[N,K]^T + bias).
// mfma_scale_f32_32x32x64_f8f6f4, identity scales. Tile 128xBN, BK=128 B,
// single-buffer (16 + BN/8 KB), 2-D grid, drain loop.
// BN=128: 4 waves/256 thr (5 blk/CU). BN=256: 8 waves/512 thr (3 blk/CU,
//   24 waves) — per-wave work/VGPR identical (each wave owns 64x64).
// C/D: col=lane&31, row=(reg&3)+8*(reg>>2)+4*(lane>>5)  [m101-verified].
// OUT: 0 = fp8 (relu), 1 = bf16 no-bias no-relu (split-K partial).
// ---------------------------------------------------------------------------
template <int OUT, int BN>
__device__ __forceinline__ void fp8_gemm_core(
    const unsigned char* __restrict__ A, const unsigned char* __restrict__ B,
    const float* __restrict__ bias, unsigned char* __restrict__ C8,
    bf16_t* __restrict__ Cb, int ldab, int K, int koff, int N,
    int bxi, int byi)
{
  constexpr int NT = 2 * BN;            // threads per block
  constexpr int RPP = NT / 8;           // rows staged per pass
  constexpr int A_P = 128 / RPP;        // A passes
  constexpr int B_P = BN / RPP;         // B passes
  constexpr int PASSB = NT * 16;        // bytes per pass

  __shared__ unsigned char As[16384];
  __shared__ unsigned char Bs[BN * 128];
  const int tid = threadIdx.x;
  const int wave = tid >> 6, lane = tid & 63;
  const int wm = wave & 1, wn = wave >> 1;
  const int m = lane & 31, h = lane >> 5;
  const long row0 = (long)bxi * 128;
  const long col0 = (long)byi * BN;

  const int sr = tid >> 3;
  const int cg = (tid & 7) ^ (sr & 7);
  const unsigned char* ag = A + (row0 + sr) * (long)ldab + koff + cg * 16;
  const unsigned char* bg = B + (col0 + sr) * (long)ldab + koff + cg * 16;
  char* asD = (char*)As + wave * 1024;
  char* bsD = (char*)Bs + wave * 1024;
  const long rowsPP = (long)RPP * ldab;

  const int ar0 = wm * 64 + m, ar1 = ar0 + 32;
  const int br0 = wn * 64 + m, br1 = wn * 64 + 32 + m;

  f32x16 acc[2][2];
#pragma unroll
  for (int mi = 0; mi < 2; mi++)
#pragma unroll
    for (int nj = 0; nj < 2; nj++)
#pragma unroll
      for (int r = 0; r < 16; r++) acc[mi][nj][r] = 0.f;

  for (int k0 = 0; k0 < K; k0 += 128) {
    __syncthreads();
#pragma unroll
    for (int is = 0; is < A_P; is++)
      gload_lds16(ag + is * rowsPP + k0, asD + is * PASSB);
#pragma unroll
    for (int is = 0; is < B_P; is++)
      gload_lds16(bg + is * rowsPP + k0, bsD + is * PASSB);
    __syncthreads();
#pragma unroll
    for (int ks = 0; ks < 2; ks++) {
      const int c0 = ks * 4 + h * 2;
      i32x8_t a[2], b[2];
#pragma unroll
      for (int mi = 0; mi < 2; mi++) {
        const int r = mi ? ar1 : ar0;
        i32x4_t lo = *(const i32x4_t*)(As + r * 128 + ((c0    ) ^ (r & 7)) * 16);
        i32x4_t hi = *(const i32x4_t*)(As + r * 128 + ((c0 + 1) ^ (r & 7)) * 16);
        a[mi][0] = lo[0]; a[mi][1] = lo[1]; a[mi][2] = lo[2]; a[mi][3] = lo[3];
        a[mi][4] = hi[0]; a[mi][5] = hi[1]; a[mi][6] = hi[2]; a[mi][7] = hi[3];
      }
#pragma unroll
      for (int nj = 0; nj < 2; nj++) {
        const int r = nj ? br1 : br0;
        i32x4_t lo = *(const i32x4_t*)(Bs + r * 128 + ((c0    ) ^ (r & 7)) * 16);
        i32x4_t hi = *(const i32x4_t*)(Bs + r * 128 + ((c0 + 1) ^ (r & 7)) * 16);
        b[nj][0] = lo[0]; b[nj][1] = lo[1]; b[nj][2] = lo[2]; b[nj][3] = lo[3];
        b[nj][4] = hi[0]; b[nj][5] = hi[1]; b[nj][6] = hi[2]; b[nj][7] = hi[3];
      }
#pragma unroll
      for (int mi = 0; mi < 2; mi++)
#pragma unroll
        for (int nj = 0; nj < 2; nj++)
          acc[mi][nj] = __builtin_amdgcn_mfma_scale_f32_32x32x64_f8f6f4(
              a[mi], b[nj], acc[mi][nj], 0, 0,
              0, 0x7f7f7f7f, 0, 0x7f7f7f7f);
    }
  }

  float bc[2];
  bc[0] = bias ? bias[col0 + wn * 64 + m] : 0.f;
  bc[1] = bias ? bias[col0 + wn * 64 + 32 + m] : 0.f;
#pragma unroll
  for (int mi = 0; mi < 2; mi++)
#pragma unroll
    for (int nj = 0; nj < 2; nj++)
#pragma unroll
      for (int reg = 0; reg < 16; reg++) {
        const int rl = (reg & 3) + 8 * (reg >> 2) + 4 * h;
        const long idx = (row0 + wm * 64 + mi * 32 + rl) * (long)N
                       + col0 + wn * 64 + nj * 32 + m;
        if (OUT == 0) {
          float v = fmaxf(acc[mi][nj][reg] + bc[nj], 0.f);
          C8[idx] = to_fp8(v);
        } else {
          Cb[idx] = (bf16_t)acc[mi][nj][reg];
        }
      }
}

// FFN1: H1 = relu(X_fp8 @ W1_fp8^T + b1), fp8 out. K=512. 128x256, 512 thr.
__global__ __launch_bounds__(512) void ffn1_fp8(
    const unsigned char* __restrict__ Xq, const unsigned char* __restrict__ W1,
    const float* __restrict__ bias, unsigned char* __restrict__ C)
{
  fp8_gemm_core<0, 256>(Xq, W1, bias, C, nullptr, 512, 512, 0, 2048,
                        blockIdx.x, blockIdx.y);
}

// FFN2: H2 = relu(H1_fp8 @ W2_fp8^T + b2), fp8 out. K=2048. 128x256, 512 thr.
__global__ __launch_bounds__(512) void ffn2_fp8(
    const unsigned char* __restrict__ H1, const unsigned char* __restrict__ W2,
    const float* __restrict__ bias, unsigned char* __restrict__ C)
{
  fp8_gemm_core<0, 256>(H1, W2, bias, C, nullptr, 2048, 2048, 0, 2048,
                        blockIdx.x, blockIdx.y);
}

// FFN3 split-K (z = K-half): bf16 partials, no bias/relu. BN=128 kept
// (BN=256 would drop the grid to 1 blk/CU).
__global__ __launch_bounds__(256) void ffn3_fp8(
    const unsigned char* __restrict__ H2, const unsigned char* __restrict__ W3,
    bf16_t* __restrict__ Off01)
{
  const int z = blockIdx.z;
  fp8_gemm_core<1, 128>(H2, W3, nullptr, nullptr, Off01 + (long)z * 4194304,
                        2048, 1024, z * 1024, 512, blockIdx.x, blockIdx.y);
}

// ---------------------------------------------------------------------------
// Flash attention, fixed-max softmax (max=0). 1-D grid 512 blocks, 4 waves.
// R8: QBLK=128 per block — each wave owns two 16-row q-tiles (A at +0, B at
//     +64). K-fragments register-reused across both tiles in QK^T; PV runs
//     tile A then tile B through the shared per-wave Ps buffer. K/V dbuf +
//     counted vmcnt(8); XCD decode: 8 q-blocks per (b,h), all on one XCD.
// ---------------------------------------------------------------------------
__global__ __launch_bounds__(256) void attn(
    const bf16_t* __restrict__ Qp, const bf16_t* __restrict__ Kp,
    const bf16_t* __restrict__ VT, bf16_t* __restrict__ O)
{
  const int d0 = blockIdx.x;
  const int j  = d0 >> 3;
  const int g  = (d0 & 7) * 8 + (j >> 3);   // (b,h) group, 0..63
  const int qb = j & 7;                     // q-block of 128 rows
  const int h  = g & 7, b = g >> 3;

  const int tid = threadIdx.x;
  const int wave = tid >> 6, lane = tid & 63;
  const int lq = lane & 15, quad = lane >> 4;

  __shared__ bf16_t Ks[2][8192];
  __shared__ bf16_t VTs[2][8192];
  __shared__ bf16_t Ps[4][16 * 72];

  const long bh = (long)b * 1024;
  const int qrowA = qb * 128 + wave * 16 + lq;
  const int qrowB = qrowA + 64;

  const bf16_t* qpA = Qp + (bh + qrowA) * 512 + h * 64 + quad * 8;
  const bf16_t* qpB = Qp + (bh + qrowB) * 512 + h * 64 + quad * 8;
  const bf16x8 qfA0 = *(const bf16x8*)qpA;
  const bf16x8 qfA1 = *(const bf16x8*)(qpA + 32);
  const bf16x8 qfB0 = *(const bf16x8*)qpB;
  const bf16x8 qfB1 = *(const bf16x8*)(qpB + 32);

  f32x4 oaccA[4], oaccB[4];
#pragma unroll
  for (int t = 0; t < 4; t++) {
    oaccA[t] = (f32x4){0.f, 0.f, 0.f, 0.f};
    oaccB[t] = (f32x4){0.f, 0.f, 0.f, 0.f};
  }
  float lA = 0.f, lB = 0.f;

  const int sr = tid >> 3;
  const int cg = (tid & 7) ^ (sr & 7);
  const bf16_t* kg  = Kp + bh * 512 + h * 64;
  const bf16_t* vtg = VT + ((long)b * 8 + h) * 65536;
  const int off0 = (quad ^ (lq & 7)) * 8;

  auto stage = [&](int m0, int bi) {
    char* ksDst = (char*)(Ks[bi]) + wave * 1024;
    char* vtDst = (char*)(VTs[bi]) + wave * 1024;
#pragma unroll
    for (int s = 0; s < 2; s++) {
      gload_lds16(kg + (long)(m0 + s * 64 + sr) * 512 + cg * 8,      ksDst + s * 8192);
      gload_lds16(kg + (long)(m0 + s * 64 + sr + 32) * 512 + cg * 8, ksDst + s * 8192 + 4096);
      gload_lds16(vtg + (long)sr * 1024 + m0 + s * 64 + cg * 8,        vtDst + s * 8192);
      gload_lds16(vtg + (long)(sr + 32) * 1024 + m0 + s * 64 + cg * 8, vtDst + s * 8192 + 4096);
    }
  };

  stage(0, 0);   // prologue: tile 0 in flight (8 vmem ops)

  for (int t = 0; t < 8; ++t) {
    const int cur = t & 1;
    if (t < 7) {
      stage((t + 1) * 128, cur ^ 1);                    // 8 more in flight
      asm volatile("s_waitcnt vmcnt(8)" ::: "memory");  // tile t landed
    } else {
      asm volatile("s_waitcnt vmcnt(0)" ::: "memory");  // drain last tile
    }
    __builtin_amdgcn_s_barrier();
    __builtin_amdgcn_sched_barrier(0);

    const bf16_t* Kc = Ks[cur];
    const bf16_t* Vc = VTs[cur];

    // QK^T for both q-tiles, K-fragments loaded once.
    f32x4 stA[8], stB[8];
#pragma unroll
    for (int tt = 0; tt < 8; tt++) {
      const bf16_t* kb = Kc + (tt >> 2) * 4096 + ((tt & 3) * 16 + lq) * 64;
      bf16x8 ka0 = *(const bf16x8*)(kb + off0);
      bf16x8 ka1 = *(const bf16x8*)(kb + (off0 ^ 32));
      f32x4 sA = (f32x4){0.f, 0.f, 0.f, 0.f};
      sA = mfma16(ka0, qfA0, sA);
      sA = mfma16(ka1, qfA1, sA);
      stA[tt] = sA;
      f32x4 sB = (f32x4){0.f, 0.f, 0.f, 0.f};
      sB = mfma16(ka0, qfB0, sB);
      sB = mfma16(ka1, qfB1, sB);
      stB[tt] = sB;
    }

    float lsA = 0.f, lsB = 0.f;
#pragma unroll
    for (int tt = 0; tt < 8; tt++)
#pragma unroll
      for (int r = 0; r < 4; r++) {
        float pA = __expf(stA[tt][r]);
        stA[tt][r] = pA;
        lsA += pA;
        float pB = __expf(stB[tt][r]);
        stB[tt][r] = pB;
        lsB += pB;
      }
    lsA += __shfl_xor(lsA, 16, 64);
    lsA += __shfl_xor(lsA, 32, 64);
    lA += lsA;
    lsB += __shfl_xor(lsB, 16, 64);
    lsB += __shfl_xor(lsB, 32, 64);
    lB += lsB;

    bf16_t* pw = &Ps[wave][0];
    // ---- tile A: pack P, PV ----
#pragma unroll
    for (int hh = 0; hh < 2; hh++) {
#pragma unroll
      for (int tt = 0; tt < 4; tt++) {
        bf16x4 pv;
#pragma unroll
        for (int r = 0; r < 4; r++) pv[r] = (bf16_t)stA[hh * 4 + tt][r];
        *(bf16x4*)(pw + lq * 72 + tt * 16 + quad * 4) = pv;
      }
#pragma unroll
      for (int ks = 0; ks < 2; ks++) {
        bf16x8 pb = *(const bf16x8*)(pw + lq * 72 + ks * 32 + quad * 8);
#pragma unroll
        for (int dt = 0; dt < 4; dt++) {
          const bf16_t* vb = Vc + hh * 4096 + (dt * 16 + lq) * 64;
          bf16x8 va = *(const bf16x8*)(vb + (ks ? (off0 ^ 32) : off0));
          oaccA[dt] = mfma16(va, pb, oaccA[dt]);
        }
      }
    }
    // ---- tile B: pack P, PV (same wave-private Ps; in-wave LDS ordering) ----
#pragma unroll
    for (int hh = 0; hh < 2; hh++) {
#pragma unroll
      for (int tt = 0; tt < 4; tt++) {
        bf16x4 pv;
#pragma unroll
        for (int r = 0; r < 4; r++) pv[r] = (bf16_t)stB[hh * 4 + tt][r];
        *(bf16x4*)(pw + lq * 72 + tt * 16 + quad * 4) = pv;
      }
#pragma unroll
      for (int ks = 0; ks < 2; ks++) {
        bf16x8 pb = *(const bf16x8*)(pw + lq * 72 + ks * 32 + quad * 8);
#pragma unroll
        for (int dt = 0; dt < 4; dt++) {
          const bf16_t* vb = Vc + hh * 4096 + (dt * 16 + lq) * 64;
          bf16x8 va = *(const bf16x8*)(vb + (ks ? (off0 ^ 32) : off0));
          oaccB[dt] = mfma16(va, pb, oaccB[dt]);
        }
      }
    }

    __builtin_amdgcn_sched_barrier(0);
    __builtin_amdgcn_s_barrier();   // all waves done reading buf[cur]
  }

  const float invA = 1.f / lA;
  const float invB = 1.f / lB;
  bf16_t* opA = O + (bh + qrowA) * 512 + h * 64 + quad * 4;
  bf16_t* opB = O + (bh + qrowB) * 512 + h * 64 + quad * 4;
#pragma unroll
  for (int dt = 0; dt < 4; dt++) {
    bf16x4 vA, vB;
#pragma unroll
    for (int r = 0; r < 4; r++) {
      vA[r] = (bf16_t)(oaccA[dt][r] * invA);
      vB[r] = (bf16_t)(oaccB[dt][r] * invB);
    }
    *(bf16x4*)(opA + dt * 16) = vA;
    *(bf16x4*)(opB + dt * 16) = vB;
  }
}

// ---------------------------------------------------------------------------
// LN kernels. ln_res: out = LN(A + B)*g + beta (bf16 + fp8 out).
// ln_res3: out = LN(X + O0 + O1 + bias)*g + beta (f32 out), bf16 partials.
// ---------------------------------------------------------------------------
__device__ __forceinline__ float2 ld2(const float* p, long row, int tid) {
  return ((const float2*)(p + row * 512))[tid];
}
__device__ __forceinline__ float2 ld2(const bf16_t* p, long row, int tid) {
  bf16x2 v = *(const bf16x2*)(p + row * 512 + tid * 2);
  return make_float2((float)v[0], (float)v[1]);
}

__device__ __forceinline__ void ln_finish(
    float x0, float x1, const float* g, const float* be, int tid,
    int wave, int lane, float* of, bf16_t* ob, unsigned char* o8, long row)
{
  float s = x0 + x1, ss = x0 * x0 + x1 * x1;
#pragma unroll
  for (int off = 1; off < 64; off <<= 1) {
    s  += __shfl_xor(s,  off, 64);
    ss += __shfl_xor(ss, off, 64);
  }
  __shared__ float sm[8];
  if (lane == 0) { sm[wave] = s; sm[4 + wave] = ss; }
  __syncthreads();
  s  = sm[0] + sm[1] + sm[2] + sm[3];
  ss = sm[4] + sm[5] + sm[6] + sm[7];
  const float mu = s * (1.f / 512.f);
  const float var = ss * (1.f / 512.f) - mu * mu;
  const float rs = rsqrtf(var + 1e-5f);
  const float2 gg = ((const float2*)g)[tid];
  const float2 bb = ((const float2*)be)[tid];
  const float o0 = (x0 - mu) * rs * gg.x + bb.x;
  const float o1 = (x1 - mu) * rs * gg.y + bb.y;
  if (of) ((float2*)(of + row * 512))[tid] = make_float2(o0, o1);
  if (ob) {
    bf16x2 t; t[0] = (bf16_t)o0; t[1] = (bf16_t)o1;
    *(bf16x2*)(ob + row * 512 + tid * 2) = t;
  }
  if (o8) {
    unsigned int p = __builtin_amdgcn_cvt_pk_fp8_f32(o0, o1, 0, false);
    *(unsigned short*)(o8 + row * 512 + tid * 2) = (unsigned short)(p & 0xffffu);
  }
}

__global__ __launch_bounds__(256) void ln_res(
    const bf16_t* __restrict__ A, const bf16_t* __restrict__ Bv,
    const float* __restrict__ g, const float* __restrict__ be,
    bf16_t* __restrict__ ob, unsigned char* __restrict__ o8)
{
  const int row = blockIdx.x, tid = threadIdx.x;
  const float2 va = ld2(A,  (long)row, tid);
  const float2 vb = ld2(Bv, (long)row, tid);
  ln_finish(va.x + vb.x, va.y + vb.y, g, be, tid, tid >> 6, tid & 63,
            nullptr, ob, o8, row);
}

__global__ __launch_bounds__(256) void ln_res3(
    const bf16_t* __restrict__ X, const bf16_t* __restrict__ O0,
    const bf16_t* __restrict__ O1, const float* __restrict__ bias,
    const float* __restrict__ g, const float* __restrict__ be,
    float* __restrict__ of)
{
  const int row = blockIdx.x, tid = threadIdx.x;
  const float2 vx = ld2(X,  (long)row, tid);
  const float2 v0 = ld2(O0, (long)row, tid);
  const float2 v1 = ld2(O1, (long)row, tid);
  const float2 vb = ((const float2*)bias)[tid];
  ln_finish(vx.x + v0.x + v1.x + vb.x, vx.y + v0.y + v1.y + vb.y,
            g, be, tid, tid >> 6, tid & 63, of, nullptr, nullptr, row);
}

// ---------------------------------------------------------------------------
extern "C" void kernel_launch(void* const* d_in, const int* in_sizes, int n_in,
                              void* d_out, int out_size, void* d_ws, size_t ws_size,
                              hipStream_t stream)
{
  const float* Q   = (const float*)d_in[0];
  const float* K   = (const float*)d_in[1];
  const float* Wq  = (const float*)d_in[2];
  const float* bq  = (const float*)d_in[3];
  const float* Wk  = (const float*)d_in[4];
  const float* bk  = (const float*)d_in[5];
  const float* Wv  = (const float*)d_in[6];
  const float* bv  = (const float*)d_in[7];
  const float* W1  = (const float*)d_in[8];
  const float* b1  = (const float*)d_in[9];
  const float* W2  = (const float*)d_in[10];
  const float* b2  = (const float*)d_in[11];
  const float* W3  = (const float*)d_in[12];
  const float* b3  = (const float*)d_in[13];
  const float* g0  = (const float*)d_in[14];
  const float* be0 = (const float*)d_in[15];
  const float* g1  = (const float*)d_in[16];
  const float* be1 = (const float*)d_in[17];

  char* ws = (char*)d_ws;
  // weights (live whole run)
  bf16_t* Wqb = (bf16_t*)(ws + 0);
  bf16_t* Wkb = (bf16_t*)(ws + 524288);
  bf16_t* Wvb = (bf16_t*)(ws + 1048576);
  unsigned char* W1q = (unsigned char*)(ws + 1572864);   // 1 MiB fp8
  unsigned char* W3q = (unsigned char*)(ws + 3670016);   // 1 MiB fp8
  unsigned char* W2q = (unsigned char*)(ws + 5767168);   // 4 MiB fp8
  // activations, liveness-packed
  bf16_t* Qb  = (bf16_t*)(ws + 14155776);  // dead after proj3
  bf16_t* Kb  = (bf16_t*)(ws + 22544384);  // dead after proj3
  bf16_t* Qpb = (bf16_t*)(ws + 30932992);  // dead after LN0
  bf16_t* Kpb = (bf16_t*)(ws + 39321600);  // dead after attn
  bf16_t* VT  = (bf16_t*)(ws + 47710208);  // dead after attn
  bf16_t* Of  = (bf16_t*)(ws + 14155776);  // reuse Qb; dead after LN0
  bf16_t* Xb  = (bf16_t*)(ws + 22544384);  // reuse Kb; live till LN1
  unsigned char* Xq = (unsigned char*)(ws + 47710208);   // 4 MiB fp8; reuse VT
  unsigned char* H2q = (unsigned char*)(ws + 30932992);  // 16 MiB fp8; reuse Qpb/Kpb
  unsigned char* H1q = (unsigned char*)(ws + 64487424);  // 16 MiB fp8; dead after FFN2
  bf16_t* Off0 = (bf16_t*)(ws + 64487424); // 8 MiB; reuse H1q (dead)
  bf16_t* Off1 = (bf16_t*)(ws + 72876032); // 8 MiB
  float*  out = (float*)d_out;

  cast_all<<<15104, 256, 0, stream>>>(Q, K, Wq, Wk, Wv, W1, W2, W3,
                                      Qb, Kb, Wqb, Wkb, Wvb, W1q, W2q, W3q);
  proj3<<<dim3(64, 4, 3), 256, 0, stream>>>(Qb, Kb, Wqb, Wkb, Wvb, bq, bk, bv,
                                            Qpb, Kpb, VT);
  attn<<<dim3(512, 1, 1), 256, 0, stream>>>(Qpb, Kpb, VT, Of);
  ln_res<<<8192, 256, 0, stream>>>(Of, Qpb, g0, be0, Xb, Xq);
  ffn1_fp8<<<dim3(64, 8), 512, 0, stream>>>(Xq, W1q, b1, H1q);
  ffn2_fp8<<<dim3(64, 8), 512, 0, stream>>>(H1q, W2q, b2, H2q);
  ffn3_fp8<<<dim3(64, 4, 2), 256, 0, stream>>>(H2q, W3q, Off0);
  ln_res3<<<8192, 256, 0, stream>>>(Xb, Off0, Off1, b3, g1, be1, out);
}

// Round 10
// 250.906 us; speedup vs baseline: 1.0255x; 1.0255x over previous
//
#include <hip/hip_runtime.h>

// ---------------------------------------------------------------------------
// MAB block: Qp=Q@Wq^T+bq; Kp/Vp from K; O=softmax(QhKh^T/8)Vh; X=LN(O+Qp);
// h1=relu(X@W1^T+b1); h2=relu(h1@W2^T+b2); Off=h2@W3^T+b3; out=LN(X+Off).
// R7/R8: attn dbuf + counted vmcnt + XCD decode + QBLK=128. (44 -> ~26 us)
// R13: fp8 FFN1/FFN2/FFN3 (252.6us, absmax 0.074).
// R14: BN=256 widening: ffn2 GAIN (42.7 -> <=40.8, left top-5) but ffn1
//     LOSS (~+7us: K=512 = 4 K-iters, 8-wave lockstep amplifies drain).
// R15: (a) ffn1 back to BN=128 (measured R13 config), ffn2 keeps BN=256;
//     (b) proj3 -> dbuf 64KB + counted vmcnt(8) (R5 gemm_bt measured -17%
//     on the same K=512 bf16 shape; R9/R10 totals imply proj3+ffn3 dbuf
//     was worth ~+19us — R9's regression was ffn2's 64KB cliff alone).
// ---------------------------------------------------------------------------

typedef __bf16 bf16_t;
typedef __bf16 bf16x8 __attribute__((ext_vector_type(8)));
typedef __bf16 bf16x4 __attribute__((ext_vector_type(4)));
typedef __bf16 bf16x2 __attribute__((ext_vector_type(2)));
typedef float  f32x4  __attribute__((ext_vector_type(4)));
typedef float  f32x16 __attribute__((ext_vector_type(16)));
typedef int    i32x4_t __attribute__((ext_vector_type(4)));
typedef int    i32x8_t __attribute__((ext_vector_type(8)));

__device__ __forceinline__ f32x4 mfma16(bf16x8 a, bf16x8 b, f32x4 c) {
  return __builtin_amdgcn_mfma_f32_16x16x32_bf16(a, b, c, 0, 0, 0);
}

// async global->LDS, 16B per lane. LDS dst is wave-uniform base + lane*16.
__device__ __forceinline__ void gload_lds16(const void* g, void* l) {
  __builtin_amdgcn_global_load_lds((const __attribute__((address_space(1))) void*)g,
                                   (__attribute__((address_space(3))) void*)l,
                                   16, 0, 0);
}

__device__ __forceinline__ unsigned char to_fp8(float v) {
  return (unsigned char)(__builtin_amdgcn_cvt_pk_fp8_f32(v, v, 0, false) & 0xff);
}

// ---------------------------------------------------------------------------
// Fused f32 -> bf16 cast of Q, K, Wq/Wk/Wv; W1, W2, W3 -> fp8 e4m3.
// ---------------------------------------------------------------------------
__global__ __launch_bounds__(256) void cast_all(
    const float* __restrict__ Q, const float* __restrict__ K,
    const float* __restrict__ Wq, const float* __restrict__ Wk,
    const float* __restrict__ Wv, const float* __restrict__ W1,
    const float* __restrict__ W2, const float* __restrict__ W3,
    bf16_t* Qb, bf16_t* Kb, bf16_t* Wqb, bf16_t* Wkb, bf16_t* Wvb,
    unsigned char* W1q, unsigned char* W2q, unsigned char* W3q)
{
  long i = ((long)blockIdx.x * 256 + threadIdx.x) * 4;
  if (i >= 9175040L) {                            // W1 / W2 / W3 -> fp8
    const float* s; unsigned char* d; long o;
    if      (i < 10223616L) { s = W1; d = W1q; o = i - 9175040L;  }
    else if (i < 14417920L) { s = W2; d = W2q; o = i - 10223616L; }
    else                    { s = W3; d = W3q; o = i - 14417920L; }
    float4 v = *(const float4*)(s + o);
    unsigned int lo = __builtin_amdgcn_cvt_pk_fp8_f32(v.x, v.y, 0, false);
    unsigned int hi = __builtin_amdgcn_cvt_pk_fp8_f32(v.z, v.w, 0, false);
    *(unsigned int*)(d + o) = (lo & 0xffffu) | (hi << 16);
    return;
  }
  const float* s; bf16_t* d; long o;
  if      (i <  4194304L) { s = Q;  d = Qb;  o = i;             }
  else if (i <  8388608L) { s = K;  d = Kb;  o = i - 4194304L;  }
  else if (i <  8650752L) { s = Wq; d = Wqb; o = i - 8388608L;  }
  else if (i <  8912896L) { s = Wk; d = Wkb; o = i - 8650752L;  }
  else                    { s = Wv; d = Wvb; o = i - 8912896L;  }
  float4 v = *(const float4*)(s + o);
  bf16x4 w;
  w[0] = (bf16_t)v.x; w[1] = (bf16_t)v.y; w[2] = (bf16_t)v.z; w[3] = (bf16_t)v.w;
  *(bf16x4*)(d + o) = w;
}

// ---------------------------------------------------------------------------
// bf16 GEMM core (proj3): C = A @ W^T (+bias). BM=BN=128, BK=64.
// R15: double-buffered 2x32KB LDS + counted vmcnt(8) prefetch (2 blk/CU).
// VTEPI transpose buffer (33KB) aliases the dbuf smem after the K-loop.
// ---------------------------------------------------------------------------
template <bool VTEPI>
__device__ __forceinline__ void gemm_core(
    const bf16_t* __restrict__ A, const bf16_t* __restrict__ W,
    const float* __restrict__ bias,
    bf16_t* __restrict__ Cb, bf16_t* __restrict__ VTout,
    float bscale, int N, int K, int lda, int ldb, int bx, int by)
{
  constexpr int FI = 4;
  constexpr int FJ = 4;
  constexpr int CN = 64;
  constexpr int SM_AB = 256 * 64 * 2;             // 32 KB per buffer
  constexpr int SMEM = 2 * SM_AB;                 // 64 KB (covers 33KB Ts)

  __shared__ __align__(16) char smem[SMEM];

  const int tid  = threadIdx.x;
  const int wave = tid >> 6, lane = tid & 63;
  const int lq   = lane & 15, quad = lane >> 4;
  const int wm   = wave & 1;
  const int wn   = wave >> 1;
  const long row0 = (long)bx * 128;
  const long col0 = (long)by * 128;

  const int sr = tid >> 3;
  const int cg = (tid & 7) ^ (sr & 7);
  const bf16_t* ag = A + (row0 + sr) * (long)lda + cg * 8;
  const bf16_t* bg = W + (col0 + sr) * (long)ldb + cg * 8;
  const int asOff = wave * 1024;
  const int bsOff = 128 * 128 + wave * 1024;
  const long arows32 = 32L * lda;
  const long brows32 = 32L * ldb;

  auto stage = [&](int k0, int bi) {
    char* base = smem + bi * SM_AB;
#pragma unroll
    for (int is = 0; is < 4; is++)
      gload_lds16(ag + is * arows32 + k0, base + asOff + is * 4096);
#pragma unroll
    for (int is = 0; is < 4; is++)
      gload_lds16(bg + is * brows32 + k0, base + bsOff + is * 4096);
  };

  const int off0 = (quad ^ (lq & 7)) * 8;
  const int aO0 = ((wm * 64 + lq) * 64 + off0) * 2;
  const int aO1 = ((wm * 64 + lq) * 64 + (off0 ^ 32)) * 2;
  const int bO0 = 128 * 128 + ((wn * CN + lq) * 64 + off0) * 2;
  const int bO1 = 128 * 128 + ((wn * CN + lq) * 64 + (off0 ^ 32)) * 2;

  f32x4 acc[FI][FJ];
#pragma unroll
  for (int i = 0; i < FI; i++)
#pragma unroll
    for (int j = 0; j < FJ; j++) acc[i][j] = (f32x4){0.f, 0.f, 0.f, 0.f};

  const int nt = K >> 6;
  stage(0, 0);                       // prologue: tile 0 in flight (8 vmem)
  for (int t = 0; t < nt; ++t) {
    const int cur = t & 1;
    if (t < nt - 1) {
      stage((t + 1) * 64, cur ^ 1);                     // 8 more in flight
      asm volatile("s_waitcnt vmcnt(8)" ::: "memory");  // tile t landed
    } else {
      asm volatile("s_waitcnt vmcnt(0)" ::: "memory");  // drain last tile
    }
    __builtin_amdgcn_s_barrier();
    __builtin_amdgcn_sched_barrier(0);
    const char* base = smem + cur * SM_AB;

    bf16x8 af[FI], bw[FJ];
#pragma unroll
    for (int i = 0; i < FI; i++) af[i] = *(const bf16x8*)(base + aO0 + i * 2048);
#pragma unroll
    for (int j = 0; j < FJ; j++) bw[j] = *(const bf16x8*)(base + bO0 + j * 2048);
#pragma unroll
    for (int i = 0; i < FI; i++)
#pragma unroll
      for (int j = 0; j < FJ; j++)
        acc[i][j] = mfma16(af[i], bw[j], acc[i][j]);
#pragma unroll
    for (int i = 0; i < FI; i++) af[i] = *(const bf16x8*)(base + aO1 + i * 2048);
#pragma unroll
    for (int j = 0; j < FJ; j++) bw[j] = *(const bf16x8*)(base + bO1 + j * 2048);
#pragma unroll
    for (int i = 0; i < FI; i++)
#pragma unroll
      for (int j = 0; j < FJ; j++)
        acc[i][j] = mfma16(af[i], bw[j], acc[i][j]);

    __builtin_amdgcn_sched_barrier(0);
    __builtin_amdgcn_s_barrier();   // all waves done reading buf[cur]
  }

  float bc[FJ];
#pragma unroll
  for (int j = 0; j < FJ; j++)
    bc[j] = bias ? bias[col0 + wn * CN + j * 16 + lq] : 0.f;

  if (VTEPI && VTout) {
    bf16_t* Ts = (bf16_t*)smem;
    __syncthreads();
#pragma unroll
    for (int i = 0; i < FI; i++)
#pragma unroll
      for (int j = 0; j < FJ; j++) {
        bf16x4 pv;
#pragma unroll
        for (int r = 0; r < 4; r++) pv[r] = (bf16_t)(acc[i][j][r] + bc[j]);
        *(bf16x4*)(Ts + (wn * CN + j * 16 + lq) * 132 + wm * 64 + i * 16 + quad * 4) = pv;
      }
    __syncthreads();
    const int b  = bx >> 3;
    const int mb = (bx & 7) * 128;
    const int h0 = by * 2;
    const int dd = tid >> 4;
    const int mc = (tid & 15) * 8;
#pragma unroll
    for (int p = 0; p < 8; p++) {
      const int d = dd + p * 16;
      bf16x8 v = *(const bf16x8*)(Ts + d * 132 + mc);
      *(bf16x8*)(VTout + ((long)(b * 8 + h0 + (d >> 6))) * 65536
                 + (d & 63) * 1024 + mb + mc) = v;
    }
    return;
  }

  const long rb = row0 + wm * 64 + quad * 4;
  const long cb = col0 + wn * CN + lq;
#pragma unroll
  for (int i = 0; i < FI; i++)
#pragma unroll
    for (int j = 0; j < FJ; j++)
#pragma unroll
      for (int r = 0; r < 4; r++) {
        float v = acc[i][j][r] + bc[j];
        long idx = (rb + i * 16 + r) * (long)N + cb + j * 16;
        if (Cb) Cb[idx] = (bf16_t)(v * bscale);
      }
}

// Fused Q/K/V projection; z==2 (V) writes transposed VT via VTEPI epilogue.
__global__ __launch_bounds__(256) void proj3(
    const bf16_t* __restrict__ Qb, const bf16_t* __restrict__ Kb,
    const bf16_t* __restrict__ Wqb, const bf16_t* __restrict__ Wkb,
    const bf16_t* __restrict__ Wvb,
    const float* __restrict__ bq, const float* __restrict__ bk,
    const float* __restrict__ bv,
    bf16_t* Qpb, bf16_t* Kpb, bf16_t* VT)
{
  const int z = blockIdx.z;
  const bf16_t* A  = (z == 0) ? Qb : Kb;
  const bf16_t* Wt = (z == 0) ? Wqb : ((z == 1) ? Wkb : Wvb);
  const float* bias = (z == 0) ? bq : ((z == 1) ? bk : bv);
  bf16_t* Cb = (z == 0) ? Qpb : ((z == 1) ? Kpb : nullptr);
  bf16_t* VTout = (z == 2) ? VT : nullptr;
  const float sc = (z == 1) ? 0.125f : 1.0f;
  gemm_core<true>(A, Wt, bias, Cb, VTout, sc,
                  512, 512, 512, 512, blockIdx.x, blockIdx.y);
}

// ---------------------------------------------------------------------------
// fp8 GEMM (shared body): C[M,N] = act(A_fp8[M,K] @ B_fp8[N,K]^T + bias).
// mfma_scale_f32_32x32x64_f8f6f4, identity scales. Tile 128xBN, BK=128 B,
// single-buffer (16 + BN/8 KB), 2-D grid, drain loop.
// BN=128: 4 waves/256 thr (5 blk/CU) — best for short K (ffn1/ffn3).
// BN=256: 8 waves/512 thr (3 blk/CU) — best for long K (ffn2; R14 measured).
// C/D: col=lane&31, row=(reg&3)+8*(reg>>2)+4*(lane>>5)  [m101-verified].
// OUT: 0 = fp8 (relu), 1 = bf16 no-bias no-relu (split-K partial).
// ---------------------------------------------------------------------------
template <int OUT, int BN>
__device__ __forceinline__ void fp8_gemm_core(
    const unsigned char* __restrict__ A, const unsigned char* __restrict__ B,
    const float* __restrict__ bias, unsigned char* __restrict__ C8,
    bf16_t* __restrict__ Cb, int ldab, int K, int koff, int N,
    int bxi, int byi)
{
  constexpr int NT = 2 * BN;            // threads per block
  constexpr int RPP = NT / 8;           // rows staged per pass
  constexpr int A_P = 128 / RPP;        // A passes
  constexpr int B_P = BN / RPP;         // B passes
  constexpr int PASSB = NT * 16;        // bytes per pass

  __shared__ unsigned char As[16384];
  __shared__ unsigned char Bs[BN * 128];
  const int tid = threadIdx.x;
  const int wave = tid >> 6, lane = tid & 63;
  const int wm = wave & 1, wn = wave >> 1;
  const int m = lane & 31, h = lane >> 5;
  const long row0 = (long)bxi * 128;
  const long col0 = (long)byi * BN;

  const int sr = tid >> 3;
  const int cg = (tid & 7) ^ (sr & 7);
  const unsigned char* ag = A + (row0 + sr) * (long)ldab + koff + cg * 16;
  const unsigned char* bg = B + (col0 + sr) * (long)ldab + koff + cg * 16;
  char* asD = (char*)As + wave * 1024;
  char* bsD = (char*)Bs + wave * 1024;
  const long rowsPP = (long)RPP * ldab;

  const int ar0 = wm * 64 + m, ar1 = ar0 + 32;
  const int br0 = wn * 64 + m, br1 = wn * 64 + 32 + m;

  f32x16 acc[2][2];
#pragma unroll
  for (int mi = 0; mi < 2; mi++)
#pragma unroll
    for (int nj = 0; nj < 2; nj++)
#pragma unroll
      for (int r = 0; r < 16; r++) acc[mi][nj][r] = 0.f;

  for (int k0 = 0; k0 < K; k0 += 128) {
    __syncthreads();
#pragma unroll
    for (int is = 0; is < A_P; is++)
      gload_lds16(ag + is * rowsPP + k0, asD + is * PASSB);
#pragma unroll
    for (int is = 0; is < B_P; is++)
      gload_lds16(bg + is * rowsPP + k0, bsD + is * PASSB);
    __syncthreads();
#pragma unroll
    for (int ks = 0; ks < 2; ks++) {
      const int c0 = ks * 4 + h * 2;
      i32x8_t a[2], b[2];
#pragma unroll
      for (int mi = 0; mi < 2; mi++) {
        const int r = mi ? ar1 : ar0;
        i32x4_t lo = *(const i32x4_t*)(As + r * 128 + ((c0    ) ^ (r & 7)) * 16);
        i32x4_t hi = *(const i32x4_t*)(As + r * 128 + ((c0 + 1) ^ (r & 7)) * 16);
        a[mi][0] = lo[0]; a[mi][1] = lo[1]; a[mi][2] = lo[2]; a[mi][3] = lo[3];
        a[mi][4] = hi[0]; a[mi][5] = hi[1]; a[mi][6] = hi[2]; a[mi][7] = hi[3];
      }
#pragma unroll
      for (int nj = 0; nj < 2; nj++) {
        const int r = nj ? br1 : br0;
        i32x4_t lo = *(const i32x4_t*)(Bs + r * 128 + ((c0    ) ^ (r & 7)) * 16);
        i32x4_t hi = *(const i32x4_t*)(Bs + r * 128 + ((c0 + 1) ^ (r & 7)) * 16);
        b[nj][0] = lo[0]; b[nj][1] = lo[1]; b[nj][2] = lo[2]; b[nj][3] = lo[3];
        b[nj][4] = hi[0]; b[nj][5] = hi[1]; b[nj][6] = hi[2]; b[nj][7] = hi[3];
      }
#pragma unroll
      for (int mi = 0; mi < 2; mi++)
#pragma unroll
        for (int nj = 0; nj < 2; nj++)
          acc[mi][nj] = __builtin_amdgcn_mfma_scale_f32_32x32x64_f8f6f4(
              a[mi], b[nj], acc[mi][nj], 0, 0,
              0, 0x7f7f7f7f, 0, 0x7f7f7f7f);
    }
  }

  float bc[2];
  bc[0] = bias ? bias[col0 + wn * 64 + m] : 0.f;
  bc[1] = bias ? bias[col0 + wn * 64 + 32 + m] : 0.f;
#pragma unroll
  for (int mi = 0; mi < 2; mi++)
#pragma unroll
    for (int nj = 0; nj < 2; nj++)
#pragma unroll
      for (int reg = 0; reg < 16; reg++) {
        const int rl = (reg & 3) + 8 * (reg >> 2) + 4 * h;
        const long idx = (row0 + wm * 64 + mi * 32 + rl) * (long)N
                       + col0 + wn * 64 + nj * 32 + m;
        if (OUT == 0) {
          float v = fmaxf(acc[mi][nj][reg] + bc[nj], 0.f);
          C8[idx] = to_fp8(v);
        } else {
          Cb[idx] = (bf16_t)acc[mi][nj][reg];
        }
      }
}

// FFN1: H1 = relu(X_fp8 @ W1_fp8^T + b1), fp8 out. K=512 (4 iters): BN=128.
__global__ __launch_bounds__(256) void ffn1_fp8(
    const unsigned char* __restrict__ Xq, const unsigned char* __restrict__ W1,
    const float* __restrict__ bias, unsigned char* __restrict__ C)
{
  fp8_gemm_core<0, 128>(Xq, W1, bias, C, nullptr, 512, 512, 0, 2048,
                        blockIdx.x, blockIdx.y);
}

// FFN2: H2 = relu(H1_fp8 @ W2_fp8^T + b2), fp8 out. K=2048 (16 iters): BN=256.
__global__ __launch_bounds__(512) void ffn2_fp8(
    const unsigned char* __restrict__ H1, const unsigned char* __restrict__ W2,
    const float* __restrict__ bias, unsigned char* __restrict__ C)
{
  fp8_gemm_core<0, 256>(H1, W2, bias, C, nullptr, 2048, 2048, 0, 2048,
                        blockIdx.x, blockIdx.y);
}

// FFN3 split-K (z = K-half): bf16 partials, no bias/relu. BN=128.
__global__ __launch_bounds__(256) void ffn3_fp8(
    const unsigned char* __restrict__ H2, const unsigned char* __restrict__ W3,
    bf16_t* __restrict__ Off01)
{
  const int z = blockIdx.z;
  fp8_gemm_core<1, 128>(H2, W3, nullptr, nullptr, Off01 + (long)z * 4194304,
                        2048, 1024, z * 1024, 512, blockIdx.x, blockIdx.y);
}

// ---------------------------------------------------------------------------
// Flash attention, fixed-max softmax (max=0). 1-D grid 512 blocks, 4 waves.
// R8: QBLK=128 per block — each wave owns two 16-row q-tiles (A at +0, B at
//     +64). K-fragments register-reused across both tiles in QK^T; PV runs
//     tile A then tile B through the shared per-wave Ps buffer. K/V dbuf +
//     counted vmcnt(8); XCD decode: 8 q-blocks per (b,h), all on one XCD.
// ---------------------------------------------------------------------------
__global__ __launch_bounds__(256) void attn(
    const bf16_t* __restrict__ Qp, const bf16_t* __restrict__ Kp,
    const bf16_t* __restrict__ VT, bf16_t* __restrict__ O)
{
  const int d0 = blockIdx.x;
  const int j  = d0 >> 3;
  const int g  = (d0 & 7) * 8 + (j >> 3);   // (b,h) group, 0..63
  const int qb = j & 7;                     // q-block of 128 rows
  const int h  = g & 7, b = g >> 3;

  const int tid = threadIdx.x;
  const int wave = tid >> 6, lane = tid & 63;
  const int lq = lane & 15, quad = lane >> 4;

  __shared__ bf16_t Ks[2][8192];
  __shared__ bf16_t VTs[2][8192];
  __shared__ bf16_t Ps[4][16 * 72];

  const long bh = (long)b * 1024;
  const int qrowA = qb * 128 + wave * 16 + lq;
  const int qrowB = qrowA + 64;

  const bf16_t* qpA = Qp + (bh + qrowA) * 512 + h * 64 + quad * 8;
  const bf16_t* qpB = Qp + (bh + qrowB) * 512 + h * 64 + quad * 8;
  const bf16x8 qfA0 = *(const bf16x8*)qpA;
  const bf16x8 qfA1 = *(const bf16x8*)(qpA + 32);
  const bf16x8 qfB0 = *(const bf16x8*)qpB;
  const bf16x8 qfB1 = *(const bf16x8*)(qpB + 32);

  f32x4 oaccA[4], oaccB[4];
#pragma unroll
  for (int t = 0; t < 4; t++) {
    oaccA[t] = (f32x4){0.f, 0.f, 0.f, 0.f};
    oaccB[t] = (f32x4){0.f, 0.f, 0.f, 0.f};
  }
  float lA = 0.f, lB = 0.f;

  const int sr = tid >> 3;
  const int cg = (tid & 7) ^ (sr & 7);
  const bf16_t* kg  = Kp + bh * 512 + h * 64;
  const bf16_t* vtg = VT + ((long)b * 8 + h) * 65536;
  const int off0 = (quad ^ (lq & 7)) * 8;

  auto stage = [&](int m0, int bi) {
    char* ksDst = (char*)(Ks[bi]) + wave * 1024;
    char* vtDst = (char*)(VTs[bi]) + wave * 1024;
#pragma unroll
    for (int s = 0; s < 2; s++) {
      gload_lds16(kg + (long)(m0 + s * 64 + sr) * 512 + cg * 8,      ksDst + s * 8192);
      gload_lds16(kg + (long)(m0 + s * 64 + sr + 32) * 512 + cg * 8, ksDst + s * 8192 + 4096);
      gload_lds16(vtg + (long)sr * 1024 + m0 + s * 64 + cg * 8,        vtDst + s * 8192);
      gload_lds16(vtg + (long)(sr + 32) * 1024 + m0 + s * 64 + cg * 8, vtDst + s * 8192 + 4096);
    }
  };

  stage(0, 0);   // prologue: tile 0 in flight (8 vmem ops)

  for (int t = 0; t < 8; ++t) {
    const int cur = t & 1;
    if (t < 7) {
      stage((t + 1) * 128, cur ^ 1);                    // 8 more in flight
      asm volatile("s_waitcnt vmcnt(8)" ::: "memory");  // tile t landed
    } else {
      asm volatile("s_waitcnt vmcnt(0)" ::: "memory");  // drain last tile
    }
    __builtin_amdgcn_s_barrier();
    __builtin_amdgcn_sched_barrier(0);

    const bf16_t* Kc = Ks[cur];
    const bf16_t* Vc = VTs[cur];

    // QK^T for both q-tiles, K-fragments loaded once.
    f32x4 stA[8], stB[8];
#pragma unroll
    for (int tt = 0; tt < 8; tt++) {
      const bf16_t* kb = Kc + (tt >> 2) * 4096 + ((tt & 3) * 16 + lq) * 64;
      bf16x8 ka0 = *(const bf16x8*)(kb + off0);
      bf16x8 ka1 = *(const bf16x8*)(kb + (off0 ^ 32));
      f32x4 sA = (f32x4){0.f, 0.f, 0.f, 0.f};
      sA = mfma16(ka0, qfA0, sA);
      sA = mfma16(ka1, qfA1, sA);
      stA[tt] = sA;
      f32x4 sB = (f32x4){0.f, 0.f, 0.f, 0.f};
      sB = mfma16(ka0, qfB0, sB);
      sB = mfma16(ka1, qfB1, sB);
      stB[tt] = sB;
    }

    float lsA = 0.f, lsB = 0.f;
#pragma unroll
    for (int tt = 0; tt < 8; tt++)
#pragma unroll
      for (int r = 0; r < 4; r++) {
        float pA = __expf(stA[tt][r]);
        stA[tt][r] = pA;
        lsA += pA;
        float pB = __expf(stB[tt][r]);
        stB[tt][r] = pB;
        lsB += pB;
      }
    lsA += __shfl_xor(lsA, 16, 64);
    lsA += __shfl_xor(lsA, 32, 64);
    lA += lsA;
    lsB += __shfl_xor(lsB, 16, 64);
    lsB += __shfl_xor(lsB, 32, 64);
    lB += lsB;

    bf16_t* pw = &Ps[wave][0];
    // ---- tile A: pack P, PV ----
#pragma unroll
    for (int hh = 0; hh < 2; hh++) {
#pragma unroll
      for (int tt = 0; tt < 4; tt++) {
        bf16x4 pv;
#pragma unroll
        for (int r = 0; r < 4; r++) pv[r] = (bf16_t)stA[hh * 4 + tt][r];
        *(bf16x4*)(pw + lq * 72 + tt * 16 + quad * 4) = pv;
      }
#pragma unroll
      for (int ks = 0; ks < 2; ks++) {
        bf16x8 pb = *(const bf16x8*)(pw + lq * 72 + ks * 32 + quad * 8);
#pragma unroll
        for (int dt = 0; dt < 4; dt++) {
          const bf16_t* vb = Vc + hh * 4096 + (dt * 16 + lq) * 64;
          bf16x8 va = *(const bf16x8*)(vb + (ks ? (off0 ^ 32) : off0));
          oaccA[dt] = mfma16(va, pb, oaccA[dt]);
        }
      }
    }
    // ---- tile B: pack P, PV (same wave-private Ps; in-wave LDS ordering) ----
#pragma unroll
    for (int hh = 0; hh < 2; hh++) {
#pragma unroll
      for (int tt = 0; tt < 4; tt++) {
        bf16x4 pv;
#pragma unroll
        for (int r = 0; r < 4; r++) pv[r] = (bf16_t)stB[hh * 4 + tt][r];
        *(bf16x4*)(pw + lq * 72 + tt * 16 + quad * 4) = pv;
      }
#pragma unroll
      for (int ks = 0; ks < 2; ks++) {
        bf16x8 pb = *(const bf16x8*)(pw + lq * 72 + ks * 32 + quad * 8);
#pragma unroll
        for (int dt = 0; dt < 4; dt++) {
          const bf16_t* vb = Vc + hh * 4096 + (dt * 16 + lq) * 64;
          bf16x8 va = *(const bf16x8*)(vb + (ks ? (off0 ^ 32) : off0));
          oaccB[dt] = mfma16(va, pb, oaccB[dt]);
        }
      }
    }

    __builtin_amdgcn_sched_barrier(0);
    __builtin_amdgcn_s_barrier();   // all waves done reading buf[cur]
  }

  const float invA = 1.f / lA;
  const float invB = 1.f / lB;
  bf16_t* opA = O + (bh + qrowA) * 512 + h * 64 + quad * 4;
  bf16_t* opB = O + (bh + qrowB) * 512 + h * 64 + quad * 4;
#pragma unroll
  for (int dt = 0; dt < 4; dt++) {
    bf16x4 vA, vB;
#pragma unroll
    for (int r = 0; r < 4; r++) {
      vA[r] = (bf16_t)(oaccA[dt][r] * invA);
      vB[r] = (bf16_t)(oaccB[dt][r] * invB);
    }
    *(bf16x4*)(opA + dt * 16) = vA;
    *(bf16x4*)(opB + dt * 16) = vB;
  }
}

// ---------------------------------------------------------------------------
// LN kernels. ln_res: out = LN(A + B)*g + beta (bf16 + fp8 out).
// ln_res3: out = LN(X + O0 + O1 + bias)*g + beta (f32 out), bf16 partials.
// ---------------------------------------------------------------------------
__device__ __forceinline__ float2 ld2(const float* p, long row, int tid) {
  return ((const float2*)(p + row * 512))[tid];
}
__device__ __forceinline__ float2 ld2(const bf16_t* p, long row, int tid) {
  bf16x2 v = *(const bf16x2*)(p + row * 512 + tid * 2);
  return make_float2((float)v[0], (float)v[1]);
}

__device__ __forceinline__ void ln_finish(
    float x0, float x1, const float* g, const float* be, int tid,
    int wave, int lane, float* of, bf16_t* ob, unsigned char* o8, long row)
{
  float s = x0 + x1, ss = x0 * x0 + x1 * x1;
#pragma unroll
  for (int off = 1; off < 64; off <<= 1) {
    s  += __shfl_xor(s,  off, 64);
    ss += __shfl_xor(ss, off, 64);
  }
  __shared__ float sm[8];
  if (lane == 0) { sm[wave] = s; sm[4 + wave] = ss; }
  __syncthreads();
  s  = sm[0] + sm[1] + sm[2] + sm[3];
  ss = sm[4] + sm[5] + sm[6] + sm[7];
  const float mu = s * (1.f / 512.f);
  const float var = ss * (1.f / 512.f) - mu * mu;
  const float rs = rsqrtf(var + 1e-5f);
  const float2 gg = ((const float2*)g)[tid];
  const float2 bb = ((const float2*)be)[tid];
  const float o0 = (x0 - mu) * rs * gg.x + bb.x;
  const float o1 = (x1 - mu) * rs * gg.y + bb.y;
  if (of) ((float2*)(of + row * 512))[tid] = make_float2(o0, o1);
  if (ob) {
    bf16x2 t; t[0] = (bf16_t)o0; t[1] = (bf16_t)o1;
    *(bf16x2*)(ob + row * 512 + tid * 2) = t;
  }
  if (o8) {
    unsigned int p = __builtin_amdgcn_cvt_pk_fp8_f32(o0, o1, 0, false);
    *(unsigned short*)(o8 + row * 512 + tid * 2) = (unsigned short)(p & 0xffffu);
  }
}

__global__ __launch_bounds__(256) void ln_res(
    const bf16_t* __restrict__ A, const bf16_t* __restrict__ Bv,
    const float* __restrict__ g, const float* __restrict__ be,
    bf16_t* __restrict__ ob, unsigned char* __restrict__ o8)
{
  const int row = blockIdx.x, tid = threadIdx.x;
  const float2 va = ld2(A,  (long)row, tid);
  const float2 vb = ld2(Bv, (long)row, tid);
  ln_finish(va.x + vb.x, va.y + vb.y, g, be, tid, tid >> 6, tid & 63,
            nullptr, ob, o8, row);
}

__global__ __launch_bounds__(256) void ln_res3(
    const bf16_t* __restrict__ X, const bf16_t* __restrict__ O0,
    const bf16_t* __restrict__ O1, const float* __restrict__ bias,
    const float* __restrict__ g, const float* __restrict__ be,
    float* __restrict__ of)
{
  const int row = blockIdx.x, tid = threadIdx.x;
  const float2 vx = ld2(X,  (long)row, tid);
  const float2 v0 = ld2(O0, (long)row, tid);
  const float2 v1 = ld2(O1, (long)row, tid);
  const float2 vb = ((const float2*)bias)[tid];
  ln_finish(vx.x + v0.x + v1.x + vb.x, vx.y + v0.y + v1.y + vb.y,
            g, be, tid, tid >> 6, tid & 63, of, nullptr, nullptr, row);
}

// ---------------------------------------------------------------------------
extern "C" void kernel_launch(void* const* d_in, const int* in_sizes, int n_in,
                              void* d_out, int out_size, void* d_ws, size_t ws_size,
                              hipStream_t stream)
{
  const float* Q   = (const float*)d_in[0];
  const float* K   = (const float*)d_in[1];
  const float* Wq  = (const float*)d_in[2];
  const float* bq  = (const float*)d_in[3];
  const float* Wk  = (const float*)d_in[4];
  const float* bk  = (const float*)d_in[5];
  const float* Wv  = (const float*)d_in[6];
  const float* bv  = (const float*)d_in[7];
  const float* W1  = (const float*)d_in[8];
  const float* b1  = (const float*)d_in[9];
  const float* W2  = (const float*)d_in[10];
  const float* b2  = (const float*)d_in[11];
  const float* W3  = (const float*)d_in[12];
  const float* b3  = (const float*)d_in[13];
  const float* g0  = (const float*)d_in[14];
  const float* be0 = (const float*)d_in[15];
  const float* g1  = (const float*)d_in[16];
  const float* be1 = (const float*)d_in[17];

  char* ws = (char*)d_ws;
  // weights (live whole run)
  bf16_t* Wqb = (bf16_t*)(ws + 0);
  bf16_t* Wkb = (bf16_t*)(ws + 524288);
  bf16_t* Wvb = (bf16_t*)(ws + 1048576);
  unsigned char* W1q = (unsigned char*)(ws + 1572864);   // 1 MiB fp8
  unsigned char* W3q = (unsigned char*)(ws + 3670016);   // 1 MiB fp8
  unsigned char* W2q = (unsigned char*)(ws + 5767168);   // 4 MiB fp8
  // activations, liveness-packed
  bf16_t* Qb  = (bf16_t*)(ws + 14155776);  // dead after proj3
  bf16_t* Kb  = (bf16_t*)(ws + 22544384);  // dead after proj3
  bf16_t* Qpb = (bf16_t*)(ws + 30932992);  // dead after LN0
  bf16_t* Kpb = (bf16_t*)(ws + 39321600);  // dead after attn
  bf16_t* VT  = (bf16_t*)(ws + 47710208);  // dead after attn
  bf16_t* Of  = (bf16_t*)(ws + 14155776);  // reuse Qb; dead after LN0
  bf16_t* Xb  = (bf16_t*)(ws + 22544384);  // reuse Kb; live till LN1
  unsigned char* Xq = (unsigned char*)(ws + 47710208);   // 4 MiB fp8; reuse VT
  unsigned char* H2q = (unsigned char*)(ws + 30932992);  // 16 MiB fp8; reuse Qpb/Kpb
  unsigned char* H1q = (unsigned char*)(ws + 64487424);  // 16 MiB fp8; dead after FFN2
  bf16_t* Off0 = (bf16_t*)(ws + 64487424); // 8 MiB; reuse H1q (dead)
  bf16_t* Off1 = (bf16_t*)(ws + 72876032); // 8 MiB
  float*  out = (float*)d_out;

  cast_all<<<15104, 256, 0, stream>>>(Q, K, Wq, Wk, Wv, W1, W2, W3,
                                      Qb, Kb, Wqb, Wkb, Wvb, W1q, W2q, W3q);
  proj3<<<dim3(64, 4, 3), 256, 0, stream>>>(Qb, Kb, Wqb, Wkb, Wvb, bq, bk, bv,
                                            Qpb, Kpb, VT);
  attn<<<dim3(512, 1, 1), 256, 0, stream>>>(Qpb, Kpb, VT, Of);
  ln_res<<<8192, 256, 0, stream>>>(Of, Qpb, g0, be0, Xb, Xq);
  ffn1_fp8<<<dim3(64, 16), 256, 0, stream>>>(Xq, W1q, b1, H1q);
  ffn2_fp8<<<dim3(64, 8), 512, 0, stream>>>(H1q, W2q, b2, H2q);
  ffn3_fp8<<<dim3(64, 4, 2), 256, 0, stream>>>(H2q, W3q, Off0);
  ln_res3<<<8192, 256, 0, stream>>>(Xb, Off0, Off1, b3, g1, be1, out);
}

// Round 11
// 248.256 us; speedup vs baseline: 1.0364x; 1.0107x over previous
//
#include <hip/hip_runtime.h>

// ---------------------------------------------------------------------------
// MAB block: Qp=Q@Wq^T+bq; Kp/Vp from K; O=softmax(QhKh^T/8)Vh; X=LN(O+Qp);
// h1=relu(X@W1^T+b1); h2=relu(h1@W2^T+b2); Off=h2@W3^T+b3; out=LN(X+Off).
// R7/R8: attn dbuf + counted vmcnt + XCD decode + QBLK=128.
// R13: fp8 FFN1/FFN2/FFN3. R14: ffn2 BN=256. R15: proj3 dbuf (250.9us).
// R16: attn m-tile 128 -> 64: LDS 66.25 -> 41KB = 3 blk/CU (1.5x TLP),
//     staging 4 loads/iter + vmcnt(4), 16 iters. Counted-vmcnt dbuf kept;
//     per-barrier compute (32 MFMA + softmax VALU) stays ~2x R11's failure
//     threshold. Grid/decode/Q handling unchanged.
// ---------------------------------------------------------------------------

typedef __bf16 bf16_t;
typedef __bf16 bf16x8 __attribute__((ext_vector_type(8)));
typedef __bf16 bf16x4 __attribute__((ext_vector_type(4)));
typedef __bf16 bf16x2 __attribute__((ext_vector_type(2)));
typedef float  f32x4  __attribute__((ext_vector_type(4)));
typedef float  f32x16 __attribute__((ext_vector_type(16)));
typedef int    i32x4_t __attribute__((ext_vector_type(4)));
typedef int    i32x8_t __attribute__((ext_vector_type(8)));

__device__ __forceinline__ f32x4 mfma16(bf16x8 a, bf16x8 b, f32x4 c) {
  return __builtin_amdgcn_mfma_f32_16x16x32_bf16(a, b, c, 0, 0, 0);
}

// async global->LDS, 16B per lane. LDS dst is wave-uniform base + lane*16.
__device__ __forceinline__ void gload_lds16(const void* g, void* l) {
  __builtin_amdgcn_global_load_lds((const __attribute__((address_space(1))) void*)g,
                                   (__attribute__((address_space(3))) void*)l,
                                   16, 0, 0);
}

__device__ __forceinline__ unsigned char to_fp8(float v) {
  return (unsigned char)(__builtin_amdgcn_cvt_pk_fp8_f32(v, v, 0, false) & 0xff);
}

// ---------------------------------------------------------------------------
// Fused f32 -> bf16 cast of Q, K, Wq/Wk/Wv; W1, W2, W3 -> fp8 e4m3.
// ---------------------------------------------------------------------------
__global__ __launch_bounds__(256) void cast_all(
    const float* __restrict__ Q, const float* __restrict__ K,
    const float* __restrict__ Wq, const float* __restrict__ Wk,
    const float* __restrict__ Wv, const float* __restrict__ W1,
    const float* __restrict__ W2, const float* __restrict__ W3,
    bf16_t* Qb, bf16_t* Kb, bf16_t* Wqb, bf16_t* Wkb, bf16_t* Wvb,
    unsigned char* W1q, unsigned char* W2q, unsigned char* W3q)
{
  long i = ((long)blockIdx.x * 256 + threadIdx.x) * 4;
  if (i >= 9175040L) {                            // W1 / W2 / W3 -> fp8
    const float* s; unsigned char* d; long o;
    if      (i < 10223616L) { s = W1; d = W1q; o = i - 9175040L;  }
    else if (i < 14417920L) { s = W2; d = W2q; o = i - 10223616L; }
    else                    { s = W3; d = W3q; o = i - 14417920L; }
    float4 v = *(const float4*)(s + o);
    unsigned int lo = __builtin_amdgcn_cvt_pk_fp8_f32(v.x, v.y, 0, false);
    unsigned int hi = __builtin_amdgcn_cvt_pk_fp8_f32(v.z, v.w, 0, false);
    *(unsigned int*)(d + o) = (lo & 0xffffu) | (hi << 16);
    return;
  }
  const float* s; bf16_t* d; long o;
  if      (i <  4194304L) { s = Q;  d = Qb;  o = i;             }
  else if (i <  8388608L) { s = K;  d = Kb;  o = i - 4194304L;  }
  else if (i <  8650752L) { s = Wq; d = Wqb; o = i - 8388608L;  }
  else if (i <  8912896L) { s = Wk; d = Wkb; o = i - 8650752L;  }
  else                    { s = Wv; d = Wvb; o = i - 8912896L;  }
  float4 v = *(const float4*)(s + o);
  bf16x4 w;
  w[0] = (bf16_t)v.x; w[1] = (bf16_t)v.y; w[2] = (bf16_t)v.z; w[3] = (bf16_t)v.w;
  *(bf16x4*)(d + o) = w;
}

// ---------------------------------------------------------------------------
// bf16 GEMM core (proj3): C = A @ W^T (+bias). BM=BN=128, BK=64.
// R15: double-buffered 2x32KB LDS + counted vmcnt(8) prefetch (2 blk/CU).
// VTEPI transpose buffer (33KB) aliases the dbuf smem after the K-loop.
// ---------------------------------------------------------------------------
template <bool VTEPI>
__device__ __forceinline__ void gemm_core(
    const bf16_t* __restrict__ A, const bf16_t* __restrict__ W,
    const float* __restrict__ bias,
    bf16_t* __restrict__ Cb, bf16_t* __restrict__ VTout,
    float bscale, int N, int K, int lda, int ldb, int bx, int by)
{
  constexpr int FI = 4;
  constexpr int FJ = 4;
  constexpr int CN = 64;
  constexpr int SM_AB = 256 * 64 * 2;             // 32 KB per buffer
  constexpr int SMEM = 2 * SM_AB;                 // 64 KB (covers 33KB Ts)

  __shared__ __align__(16) char smem[SMEM];

  const int tid  = threadIdx.x;
  const int wave = tid >> 6, lane = tid & 63;
  const int lq   = lane & 15, quad = lane >> 4;
  const int wm   = wave & 1;
  const int wn   = wave >> 1;
  const long row0 = (long)bx * 128;
  const long col0 = (long)by * 128;

  const int sr = tid >> 3;
  const int cg = (tid & 7) ^ (sr & 7);
  const bf16_t* ag = A + (row0 + sr) * (long)lda + cg * 8;
  const bf16_t* bg = W + (col0 + sr) * (long)ldb + cg * 8;
  const int asOff = wave * 1024;
  const int bsOff = 128 * 128 + wave * 1024;
  const long arows32 = 32L * lda;
  const long brows32 = 32L * ldb;

  auto stage = [&](int k0, int bi) {
    char* base = smem + bi * SM_AB;
#pragma unroll
    for (int is = 0; is < 4; is++)
      gload_lds16(ag + is * arows32 + k0, base + asOff + is * 4096);
#pragma unroll
    for (int is = 0; is < 4; is++)
      gload_lds16(bg + is * brows32 + k0, base + bsOff + is * 4096);
  };

  const int off0 = (quad ^ (lq & 7)) * 8;
  const int aO0 = ((wm * 64 + lq) * 64 + off0) * 2;
  const int aO1 = ((wm * 64 + lq) * 64 + (off0 ^ 32)) * 2;
  const int bO0 = 128 * 128 + ((wn * CN + lq) * 64 + off0) * 2;
  const int bO1 = 128 * 128 + ((wn * CN + lq) * 64 + (off0 ^ 32)) * 2;

  f32x4 acc[FI][FJ];
#pragma unroll
  for (int i = 0; i < FI; i++)
#pragma unroll
    for (int j = 0; j < FJ; j++) acc[i][j] = (f32x4){0.f, 0.f, 0.f, 0.f};

  const int nt = K >> 6;
  stage(0, 0);                       // prologue: tile 0 in flight (8 vmem)
  for (int t = 0; t < nt; ++t) {
    const int cur = t & 1;
    if (t < nt - 1) {
      stage((t + 1) * 64, cur ^ 1);                     // 8 more in flight
      asm volatile("s_waitcnt vmcnt(8)" ::: "memory");  // tile t landed
    } else {
      asm volatile("s_waitcnt vmcnt(0)" ::: "memory");  // drain last tile
    }
    __builtin_amdgcn_s_barrier();
    __builtin_amdgcn_sched_barrier(0);
    const char* base = smem + cur * SM_AB;

    bf16x8 af[FI], bw[FJ];
#pragma unroll
    for (int i = 0; i < FI; i++) af[i] = *(const bf16x8*)(base + aO0 + i * 2048);
#pragma unroll
    for (int j = 0; j < FJ; j++) bw[j] = *(const bf16x8*)(base + bO0 + j * 2048);
#pragma unroll
    for (int i = 0; i < FI; i++)
#pragma unroll
      for (int j = 0; j < FJ; j++)
        acc[i][j] = mfma16(af[i], bw[j], acc[i][j]);
#pragma unroll
    for (int i = 0; i < FI; i++) af[i] = *(const bf16x8*)(base + aO1 + i * 2048);
#pragma unroll
    for (int j = 0; j < FJ; j++) bw[j] = *(const bf16x8*)(base + bO1 + j * 2048);
#pragma unroll
    for (int i = 0; i < FI; i++)
#pragma unroll
      for (int j = 0; j < FJ; j++)
        acc[i][j] = mfma16(af[i], bw[j], acc[i][j]);

    __builtin_amdgcn_sched_barrier(0);
    __builtin_amdgcn_s_barrier();   // all waves done reading buf[cur]
  }

  float bc[FJ];
#pragma unroll
  for (int j = 0; j < FJ; j++)
    bc[j] = bias ? bias[col0 + wn * CN + j * 16 + lq] : 0.f;

  if (VTEPI && VTout) {
    bf16_t* Ts = (bf16_t*)smem;
    __syncthreads();
#pragma unroll
    for (int i = 0; i < FI; i++)
#pragma unroll
      for (int j = 0; j < FJ; j++) {
        bf16x4 pv;
#pragma unroll
        for (int r = 0; r < 4; r++) pv[r] = (bf16_t)(acc[i][j][r] + bc[j]);
        *(bf16x4*)(Ts + (wn * CN + j * 16 + lq) * 132 + wm * 64 + i * 16 + quad * 4) = pv;
      }
    __syncthreads();
    const int b  = bx >> 3;
    const int mb = (bx & 7) * 128;
    const int h0 = by * 2;
    const int dd = tid >> 4;
    const int mc = (tid & 15) * 8;
#pragma unroll
    for (int p = 0; p < 8; p++) {
      const int d = dd + p * 16;
      bf16x8 v = *(const bf16x8*)(Ts + d * 132 + mc);
      *(bf16x8*)(VTout + ((long)(b * 8 + h0 + (d >> 6))) * 65536
                 + (d & 63) * 1024 + mb + mc) = v;
    }
    return;
  }

  const long rb = row0 + wm * 64 + quad * 4;
  const long cb = col0 + wn * CN + lq;
#pragma unroll
  for (int i = 0; i < FI; i++)
#pragma unroll
    for (int j = 0; j < FJ; j++)
#pragma unroll
      for (int r = 0; r < 4; r++) {
        float v = acc[i][j][r] + bc[j];
        long idx = (rb + i * 16 + r) * (long)N + cb + j * 16;
        if (Cb) Cb[idx] = (bf16_t)(v * bscale);
      }
}

// Fused Q/K/V projection; z==2 (V) writes transposed VT via VTEPI epilogue.
__global__ __launch_bounds__(256) void proj3(
    const bf16_t* __restrict__ Qb, const bf16_t* __restrict__ Kb,
    const bf16_t* __restrict__ Wqb, const bf16_t* __restrict__ Wkb,
    const bf16_t* __restrict__ Wvb,
    const float* __restrict__ bq, const float* __restrict__ bk,
    const float* __restrict__ bv,
    bf16_t* Qpb, bf16_t* Kpb, bf16_t* VT)
{
  const int z = blockIdx.z;
  const bf16_t* A  = (z == 0) ? Qb : Kb;
  const bf16_t* Wt = (z == 0) ? Wqb : ((z == 1) ? Wkb : Wvb);
  const float* bias = (z == 0) ? bq : ((z == 1) ? bk : bv);
  bf16_t* Cb = (z == 0) ? Qpb : ((z == 1) ? Kpb : nullptr);
  bf16_t* VTout = (z == 2) ? VT : nullptr;
  const float sc = (z == 1) ? 0.125f : 1.0f;
  gemm_core<true>(A, Wt, bias, Cb, VTout, sc,
                  512, 512, 512, 512, blockIdx.x, blockIdx.y);
}

// ---------------------------------------------------------------------------
// fp8 GEMM (shared body): C[M,N] = act(A_fp8[M,K] @ B_fp8[N,K]^T + bias).
// mfma_scale_f32_32x32x64_f8f6f4, identity scales. Tile 128xBN, BK=128 B,
// single-buffer (16 + BN/8 KB), 2-D grid, drain loop.
// BN=128: 4 waves/256 thr (5 blk/CU) — best for short K (ffn1/ffn3).
// BN=256: 8 waves/512 thr (3 blk/CU) — best for long K (ffn2; R14 measured).
// C/D: col=lane&31, row=(reg&3)+8*(reg>>2)+4*(lane>>5)  [m101-verified].
// OUT: 0 = fp8 (relu), 1 = bf16 no-bias no-relu (split-K partial).
// ---------------------------------------------------------------------------
template <int OUT, int BN>
__device__ __forceinline__ void fp8_gemm_core(
    const unsigned char* __restrict__ A, const unsigned char* __restrict__ B,
    const float* __restrict__ bias, unsigned char* __restrict__ C8,
    bf16_t* __restrict__ Cb, int ldab, int K, int koff, int N,
    int bxi, int byi)
{
  constexpr int NT = 2 * BN;            // threads per block
  constexpr int RPP = NT / 8;           // rows staged per pass
  constexpr int A_P = 128 / RPP;        // A passes
  constexpr int B_P = BN / RPP;         // B passes
  constexpr int PASSB = NT * 16;        // bytes per pass

  __shared__ unsigned char As[16384];
  __shared__ unsigned char Bs[BN * 128];
  const int tid = threadIdx.x;
  const int wave = tid >> 6, lane = tid & 63;
  const int wm = wave & 1, wn = wave >> 1;
  const int m = lane & 31, h = lane >> 5;
  const long row0 = (long)bxi * 128;
  const long col0 = (long)byi * BN;

  const int sr = tid >> 3;
  const int cg = (tid & 7) ^ (sr & 7);
  const unsigned char* ag = A + (row0 + sr) * (long)ldab + koff + cg * 16;
  const unsigned char* bg = B + (col0 + sr) * (long)ldab + koff + cg * 16;
  char* asD = (char*)As + wave * 1024;
  char* bsD = (char*)Bs + wave * 1024;
  const long rowsPP = (long)RPP * ldab;

  const int ar0 = wm * 64 + m, ar1 = ar0 + 32;
  const int br0 = wn * 64 + m, br1 = wn * 64 + 32 + m;

  f32x16 acc[2][2];
#pragma unroll
  for (int mi = 0; mi < 2; mi++)
#pragma unroll
    for (int nj = 0; nj < 2; nj++)
#pragma unroll
      for (int r = 0; r < 16; r++) acc[mi][nj][r] = 0.f;

  for (int k0 = 0; k0 < K; k0 += 128) {
    __syncthreads();
#pragma unroll
    for (int is = 0; is < A_P; is++)
      gload_lds16(ag + is * rowsPP + k0, asD + is * PASSB);
#pragma unroll
    for (int is = 0; is < B_P; is++)
      gload_lds16(bg + is * rowsPP + k0, bsD + is * PASSB);
    __syncthreads();
#pragma unroll
    for (int ks = 0; ks < 2; ks++) {
      const int c0 = ks * 4 + h * 2;
      i32x8_t a[2], b[2];
#pragma unroll
      for (int mi = 0; mi < 2; mi++) {
        const int r = mi ? ar1 : ar0;
        i32x4_t lo = *(const i32x4_t*)(As + r * 128 + ((c0    ) ^ (r & 7)) * 16);
        i32x4_t hi = *(const i32x4_t*)(As + r * 128 + ((c0 + 1) ^ (r & 7)) * 16);
        a[mi][0] = lo[0]; a[mi][1] = lo[1]; a[mi][2] = lo[2]; a[mi][3] = lo[3];
        a[mi][4] = hi[0]; a[mi][5] = hi[1]; a[mi][6] = hi[2]; a[mi][7] = hi[3];
      }
#pragma unroll
      for (int nj = 0; nj < 2; nj++) {
        const int r = nj ? br1 : br0;
        i32x4_t lo = *(const i32x4_t*)(Bs + r * 128 + ((c0    ) ^ (r & 7)) * 16);
        i32x4_t hi = *(const i32x4_t*)(Bs + r * 128 + ((c0 + 1) ^ (r & 7)) * 16);
        b[nj][0] = lo[0]; b[nj][1] = lo[1]; b[nj][2] = lo[2]; b[nj][3] = lo[3];
        b[nj][4] = hi[0]; b[nj][5] = hi[1]; b[nj][6] = hi[2]; b[nj][7] = hi[3];
      }
#pragma unroll
      for (int mi = 0; mi < 2; mi++)
#pragma unroll
        for (int nj = 0; nj < 2; nj++)
          acc[mi][nj] = __builtin_amdgcn_mfma_scale_f32_32x32x64_f8f6f4(
              a[mi], b[nj], acc[mi][nj], 0, 0,
              0, 0x7f7f7f7f, 0, 0x7f7f7f7f);
    }
  }

  float bc[2];
  bc[0] = bias ? bias[col0 + wn * 64 + m] : 0.f;
  bc[1] = bias ? bias[col0 + wn * 64 + 32 + m] : 0.f;
#pragma unroll
  for (int mi = 0; mi < 2; mi++)
#pragma unroll
    for (int nj = 0; nj < 2; nj++)
#pragma unroll
      for (int reg = 0; reg < 16; reg++) {
        const int rl = (reg & 3) + 8 * (reg >> 2) + 4 * h;
        const long idx = (row0 + wm * 64 + mi * 32 + rl) * (long)N
                       + col0 + wn * 64 + nj * 32 + m;
        if (OUT == 0) {
          float v = fmaxf(acc[mi][nj][reg] + bc[nj], 0.f);
          C8[idx] = to_fp8(v);
        } else {
          Cb[idx] = (bf16_t)acc[mi][nj][reg];
        }
      }
}

// FFN1: H1 = relu(X_fp8 @ W1_fp8^T + b1), fp8 out. K=512 (4 iters): BN=128.
__global__ __launch_bounds__(256) void ffn1_fp8(
    const unsigned char* __restrict__ Xq, const unsigned char* __restrict__ W1,
    const float* __restrict__ bias, unsigned char* __restrict__ C)
{
  fp8_gemm_core<0, 128>(Xq, W1, bias, C, nullptr, 512, 512, 0, 2048,
                        blockIdx.x, blockIdx.y);
}

// FFN2: H2 = relu(H1_fp8 @ W2_fp8^T + b2), fp8 out. K=2048 (16 iters): BN=256.
__global__ __launch_bounds__(512) void ffn2_fp8(
    const unsigned char* __restrict__ H1, const unsigned char* __restrict__ W2,
    const float* __restrict__ bias, unsigned char* __restrict__ C)
{
  fp8_gemm_core<0, 256>(H1, W2, bias, C, nullptr, 2048, 2048, 0, 2048,
                        blockIdx.x, blockIdx.y);
}

// FFN3 split-K (z = K-half): bf16 partials, no bias/relu. BN=128.
__global__ __launch_bounds__(256) void ffn3_fp8(
    const unsigned char* __restrict__ H2, const unsigned char* __restrict__ W3,
    bf16_t* __restrict__ Off01)
{
  const int z = blockIdx.z;
  fp8_gemm_core<1, 128>(H2, W3, nullptr, nullptr, Off01 + (long)z * 4194304,
                        2048, 1024, z * 1024, 512, blockIdx.x, blockIdx.y);
}

// ---------------------------------------------------------------------------
// Flash attention, fixed-max softmax (max=0). 1-D grid 512 blocks, 4 waves.
// R8: QBLK=128 per block — each wave owns two 16-row q-tiles (A at +0, B at
//     +64). K-fragments register-reused across both tiles in QK^T.
// R16: m-tile 64 (was 128): LDS 41KB -> 3 blk/CU; 16 iters, 4 loads/iter,
//     counted vmcnt(4). XCD decode: 8 q-blocks per (b,h), all on one XCD.
// ---------------------------------------------------------------------------
__global__ __launch_bounds__(256) void attn(
    const bf16_t* __restrict__ Qp, const bf16_t* __restrict__ Kp,
    const bf16_t* __restrict__ VT, bf16_t* __restrict__ O)
{
  const int d0 = blockIdx.x;
  const int j  = d0 >> 3;
  const int g  = (d0 & 7) * 8 + (j >> 3);   // (b,h) group, 0..63
  const int qb = j & 7;                     // q-block of 128 rows
  const int h  = g & 7, b = g >> 3;

  const int tid = threadIdx.x;
  const int wave = tid >> 6, lane = tid & 63;
  const int lq = lane & 15, quad = lane >> 4;

  __shared__ bf16_t Ks[2][4096];
  __shared__ bf16_t VTs[2][4096];
  __shared__ bf16_t Ps[4][16 * 72];

  const long bh = (long)b * 1024;
  const int qrowA = qb * 128 + wave * 16 + lq;
  const int qrowB = qrowA + 64;

  const bf16_t* qpA = Qp + (bh + qrowA) * 512 + h * 64 + quad * 8;
  const bf16_t* qpB = Qp + (bh + qrowB) * 512 + h * 64 + quad * 8;
  const bf16x8 qfA0 = *(const bf16x8*)qpA;
  const bf16x8 qfA1 = *(const bf16x8*)(qpA + 32);
  const bf16x8 qfB0 = *(const bf16x8*)qpB;
  const bf16x8 qfB1 = *(const bf16x8*)(qpB + 32);

  f32x4 oaccA[4], oaccB[4];
#pragma unroll
  for (int t = 0; t < 4; t++) {
    oaccA[t] = (f32x4){0.f, 0.f, 0.f, 0.f};
    oaccB[t] = (f32x4){0.f, 0.f, 0.f, 0.f};
  }
  float lA = 0.f, lB = 0.f;

  const int sr = tid >> 3;
  const int cg = (tid & 7) ^ (sr & 7);
  const bf16_t* kg  = Kp + bh * 512 + h * 64;
  const bf16_t* vtg = VT + ((long)b * 8 + h) * 65536;
  const int off0 = (quad ^ (lq & 7)) * 8;

  auto stage = [&](int m0, int bi) {
    char* ksDst = (char*)(Ks[bi]) + wave * 1024;
    char* vtDst = (char*)(VTs[bi]) + wave * 1024;
    gload_lds16(kg + (long)(m0 + sr) * 512 + cg * 8,      ksDst);
    gload_lds16(kg + (long)(m0 + sr + 32) * 512 + cg * 8, ksDst + 4096);
    gload_lds16(vtg + (long)sr * 1024 + m0 + cg * 8,        vtDst);
    gload_lds16(vtg + (long)(sr + 32) * 1024 + m0 + cg * 8, vtDst + 4096);
  };

  stage(0, 0);   // prologue: tile 0 in flight (4 vmem ops)

  for (int t = 0; t < 16; ++t) {
    const int cur = t & 1;
    if (t < 15) {
      stage((t + 1) * 64, cur ^ 1);                     // 4 more in flight
      asm volatile("s_waitcnt vmcnt(4)" ::: "memory");  // tile t landed
    } else {
      asm volatile("s_waitcnt vmcnt(0)" ::: "memory");  // drain last tile
    }
    __builtin_amdgcn_s_barrier();
    __builtin_amdgcn_sched_barrier(0);

    const bf16_t* Kc = Ks[cur];
    const bf16_t* Vc = VTs[cur];

    // QK^T for both q-tiles, K-fragments loaded once. 64 k-rows = 4 tt.
    f32x4 stA[4], stB[4];
#pragma unroll
    for (int tt = 0; tt < 4; tt++) {
      const bf16_t* kb = Kc + (tt * 16 + lq) * 64;
      bf16x8 ka0 = *(const bf16x8*)(kb + off0);
      bf16x8 ka1 = *(const bf16x8*)(kb + (off0 ^ 32));
      f32x4 sA = (f32x4){0.f, 0.f, 0.f, 0.f};
      sA = mfma16(ka0, qfA0, sA);
      sA = mfma16(ka1, qfA1, sA);
      stA[tt] = sA;
      f32x4 sB = (f32x4){0.f, 0.f, 0.f, 0.f};
      sB = mfma16(ka0, qfB0, sB);
      sB = mfma16(ka1, qfB1, sB);
      stB[tt] = sB;
    }

    float lsA = 0.f, lsB = 0.f;
#pragma unroll
    for (int tt = 0; tt < 4; tt++)
#pragma unroll
      for (int r = 0; r < 4; r++) {
        float pA = __expf(stA[tt][r]);
        stA[tt][r] = pA;
        lsA += pA;
        float pB = __expf(stB[tt][r]);
        stB[tt][r] = pB;
        lsB += pB;
      }
    lsA += __shfl_xor(lsA, 16, 64);
    lsA += __shfl_xor(lsA, 32, 64);
    lA += lsA;
    lsB += __shfl_xor(lsB, 16, 64);
    lsB += __shfl_xor(lsB, 32, 64);
    lB += lsB;

    bf16_t* pw = &Ps[wave][0];
    // ---- tile A: pack P, PV ----
#pragma unroll
    for (int tt = 0; tt < 4; tt++) {
      bf16x4 pv;
#pragma unroll
      for (int r = 0; r < 4; r++) pv[r] = (bf16_t)stA[tt][r];
      *(bf16x4*)(pw + lq * 72 + tt * 16 + quad * 4) = pv;
    }
#pragma unroll
    for (int ks = 0; ks < 2; ks++) {
      bf16x8 pb = *(const bf16x8*)(pw + lq * 72 + ks * 32 + quad * 8);
#pragma unroll
      for (int dt = 0; dt < 4; dt++) {
        const bf16_t* vb = Vc + (dt * 16 + lq) * 64;
        bf16x8 va = *(const bf16x8*)(vb + (ks ? (off0 ^ 32) : off0));
        oaccA[dt] = mfma16(va, pb, oaccA[dt]);
      }
    }
    // ---- tile B: pack P, PV (same wave-private Ps) ----
#pragma unroll
    for (int tt = 0; tt < 4; tt++) {
      bf16x4 pv;
#pragma unroll
      for (int r = 0; r < 4; r++) pv[r] = (bf16_t)stB[tt][r];
      *(bf16x4*)(pw + lq * 72 + tt * 16 + quad * 4) = pv;
    }
#pragma unroll
    for (int ks = 0; ks < 2; ks++) {
      bf16x8 pb = *(const bf16x8*)(pw + lq * 72 + ks * 32 + quad * 8);
#pragma unroll
      for (int dt = 0; dt < 4; dt++) {
        const bf16_t* vb = Vc + (dt * 16 + lq) * 64;
        bf16x8 va = *(const bf16x8*)(vb + (ks ? (off0 ^ 32) : off0));
        oaccB[dt] = mfma16(va, pb, oaccB[dt]);
      }
    }

    __builtin_amdgcn_sched_barrier(0);
    __builtin_amdgcn_s_barrier();   // all waves done reading buf[cur]
  }

  const float invA = 1.f / lA;
  const float invB = 1.f / lB;
  bf16_t* opA = O + (bh + qrowA) * 512 + h * 64 + quad * 4;
  bf16_t* opB = O + (bh + qrowB) * 512 + h * 64 + quad * 4;
#pragma unroll
  for (int dt = 0; dt < 4; dt++) {
    bf16x4 vA, vB;
#pragma unroll
    for (int r = 0; r < 4; r++) {
      vA[r] = (bf16_t)(oaccA[dt][r] * invA);
      vB[r] = (bf16_t)(oaccB[dt][r] * invB);
    }
    *(bf16x4*)(opA + dt * 16) = vA;
    *(bf16x4*)(opB + dt * 16) = vB;
  }
}

// ---------------------------------------------------------------------------
// LN kernels. ln_res: out = LN(A + B)*g + beta (bf16 + fp8 out).
// ln_res3: out = LN(X + O0 + O1 + bias)*g + beta (f32 out), bf16 partials.
// ---------------------------------------------------------------------------
__device__ __forceinline__ float2 ld2(const float* p, long row, int tid) {
  return ((const float2*)(p + row * 512))[tid];
}
__device__ __forceinline__ float2 ld2(const bf16_t* p, long row, int tid) {
  bf16x2 v = *(const bf16x2*)(p + row * 512 + tid * 2);
  return make_float2((float)v[0], (float)v[1]);
}

__device__ __forceinline__ void ln_finish(
    float x0, float x1, const float* g, const float* be, int tid,
    int wave, int lane, float* of, bf16_t* ob, unsigned char* o8, long row)
{
  float s = x0 + x1, ss = x0 * x0 + x1 * x1;
#pragma unroll
  for (int off = 1; off < 64; off <<= 1) {
    s  += __shfl_xor(s,  off, 64);
    ss += __shfl_xor(ss, off, 64);
  }
  __shared__ float sm[8];
  if (lane == 0) { sm[wave] = s; sm[4 + wave] = ss; }
  __syncthreads();
  s  = sm[0] + sm[1] + sm[2] + sm[3];
  ss = sm[4] + sm[5] + sm[6] + sm[7];
  const float mu = s * (1.f / 512.f);
  const float var = ss * (1.f / 512.f) - mu * mu;
  const float rs = rsqrtf(var + 1e-5f);
  const float2 gg = ((const float2*)g)[tid];
  const float2 bb = ((const float2*)be)[tid];
  const float o0 = (x0 - mu) * rs * gg.x + bb.x;
  const float o1 = (x1 - mu) * rs * gg.y + bb.y;
  if (of) ((float2*)(of + row * 512))[tid] = make_float2(o0, o1);
  if (ob) {
    bf16x2 t; t[0] = (bf16_t)o0; t[1] = (bf16_t)o1;
    *(bf16x2*)(ob + row * 512 + tid * 2) = t;
  }
  if (o8) {
    unsigned int p = __builtin_amdgcn_cvt_pk_fp8_f32(o0, o1, 0, false);
    *(unsigned short*)(o8 + row * 512 + tid * 2) = (unsigned short)(p & 0xffffu);
  }
}

__global__ __launch_bounds__(256) void ln_res(
    const bf16_t* __restrict__ A, const bf16_t* __restrict__ Bv,
    const float* __restrict__ g, const float* __restrict__ be,
    bf16_t* __restrict__ ob, unsigned char* __restrict__ o8)
{
  const int row = blockIdx.x, tid = threadIdx.x;
  const float2 va = ld2(A,  (long)row, tid);
  const float2 vb = ld2(Bv, (long)row, tid);
  ln_finish(va.x + vb.x, va.y + vb.y, g, be, tid, tid >> 6, tid & 63,
            nullptr, ob, o8, row);
}

__global__ __launch_bounds__(256) void ln_res3(
    const bf16_t* __restrict__ X, const bf16_t* __restrict__ O0,
    const bf16_t* __restrict__ O1, const float* __restrict__ bias,
    const float* __restrict__ g, const float* __restrict__ be,
    float* __restrict__ of)
{
  const int row = blockIdx.x, tid = threadIdx.x;
  const float2 vx = ld2(X,  (long)row, tid);
  const float2 v0 = ld2(O0, (long)row, tid);
  const float2 v1 = ld2(O1, (long)row, tid);
  const float2 vb = ((const float2*)bias)[tid];
  ln_finish(vx.x + v0.x + v1.x + vb.x, vx.y + v0.y + v1.y + vb.y,
            g, be, tid, tid >> 6, tid & 63, of, nullptr, nullptr, row);
}

// ---------------------------------------------------------------------------
extern "C" void kernel_launch(void* const* d_in, const int* in_sizes, int n_in,
                              void* d_out, int out_size, void* d_ws, size_t ws_size,
                              hipStream_t stream)
{
  const float* Q   = (const float*)d_in[0];
  const float* K   = (const float*)d_in[1];
  const float* Wq  = (const float*)d_in[2];
  const float* bq  = (const float*)d_in[3];
  const float* Wk  = (const float*)d_in[4];
  const float* bk  = (const float*)d_in[5];
  const float* Wv  = (const float*)d_in[6];
  const float* bv  = (const float*)d_in[7];
  const float* W1  = (const float*)d_in[8];
  const float* b1  = (const float*)d_in[9];
  const float* W2  = (const float*)d_in[10];
  const float* b2  = (const float*)d_in[11];
  const float* W3  = (const float*)d_in[12];
  const float* b3  = (const float*)d_in[13];
  const float* g0  = (const float*)d_in[14];
  const float* be0 = (const float*)d_in[15];
  const float* g1  = (const float*)d_in[16];
  const float* be1 = (const float*)d_in[17];

  char* ws = (char*)d_ws;
  // weights (live whole run)
  bf16_t* Wqb = (bf16_t*)(ws + 0);
  bf16_t* Wkb = (bf16_t*)(ws + 524288);
  bf16_t* Wvb = (bf16_t*)(ws + 1048576);
  unsigned char* W1q = (unsigned char*)(ws + 1572864);   // 1 MiB fp8
  unsigned char* W3q = (unsigned char*)(ws + 3670016);   // 1 MiB fp8
  unsigned char* W2q = (unsigned char*)(ws + 5767168);   // 4 MiB fp8
  // activations, liveness-packed
  bf16_t* Qb  = (bf16_t*)(ws + 14155776);  // dead after proj3
  bf16_t* Kb  = (bf16_t*)(ws + 22544384);  // dead after proj3
  bf16_t* Qpb = (bf16_t*)(ws + 30932992);  // dead after LN0
  bf16_t* Kpb = (bf16_t*)(ws + 39321600);  // dead after attn
  bf16_t* VT  = (bf16_t*)(ws + 47710208);  // dead after attn
  bf16_t* Of  = (bf16_t*)(ws + 14155776);  // reuse Qb; dead after LN0
  bf16_t* Xb  = (bf16_t*)(ws + 22544384);  // reuse Kb; live till LN1
  unsigned char* Xq = (unsigned char*)(ws + 47710208);   // 4 MiB fp8; reuse VT
  unsigned char* H2q = (unsigned char*)(ws + 30932992);  // 16 MiB fp8; reuse Qpb/Kpb
  unsigned char* H1q = (unsigned char*)(ws + 64487424);  // 16 MiB fp8; dead after FFN2
  bf16_t* Off0 = (bf16_t*)(ws + 64487424); // 8 MiB; reuse H1q (dead)
  bf16_t* Off1 = (bf16_t*)(ws + 72876032); // 8 MiB
  float*  out = (float*)d_out;

  cast_all<<<15104, 256, 0, stream>>>(Q, K, Wq, Wk, Wv, W1, W2, W3,
                                      Qb, Kb, Wqb, Wkb, Wvb, W1q, W2q, W3q);
  proj3<<<dim3(64, 4, 3), 256, 0, stream>>>(Qb, Kb, Wqb, Wkb, Wvb, bq, bk, bv,
                                            Qpb, Kpb, VT);
  attn<<<dim3(512, 1, 1), 256, 0, stream>>>(Qpb, Kpb, VT, Of);
  ln_res<<<8192, 256, 0, stream>>>(Of, Qpb, g0, be0, Xb, Xq);
  ffn1_fp8<<<dim3(64, 16), 256, 0, stream>>>(Xq, W1q, b1, H1q);
  ffn2_fp8<<<dim3(64, 8), 512, 0, stream>>>(H1q, W2q, b2, H2q);
  ffn3_fp8<<<dim3(64, 4, 2), 256, 0, stream>>>(H2q, W3q, Off0);
  ln_res3<<<8192, 256, 0, stream>>>(Xb, Off0, Off1, b3, g1, be1, out);
}